// Round 9
// baseline (849.044 us; speedup 1.0000x reference)
//
#include <hip/hip_runtime.h>

#define NN 256
#define CC 512
#define OO 1024
#define BB 64

#define F_QR 0.1f
#define F_KR 0.1f
#define F_SVE 0.1f

typedef __attribute__((ext_vector_type(8))) short bf16x8;
typedef __attribute__((ext_vector_type(4))) float f32x4;

__device__ inline unsigned short f2bf_rne(float f) {
  unsigned u = __float_as_uint(f);
  u += 0x7fffu + ((u >> 16) & 1u);
  return (unsigned short)(u >> 16);
}

__device__ inline float bf2f(unsigned short h) {
  return __uint_as_float((unsigned)h << 16);
}

// ---------------- K0: pad rel rows 511 -> 512 ----------------
__global__ void k_relpad(const float* __restrict__ rel, float* __restrict__ relp) {
  const int row = blockIdx.x;
  const int t = threadIdx.x;
  for (int u = t; u < 511; u += 256) relp[row * 512 + u] = rel[row * 511 + u];
  if (t == 0) relp[row * 512 + 511] = 0.f;
}

// ---------------- K1: qkv GEMM (split-bf16 MFMA, verified round 5) ----------------
__global__ __launch_bounds__(256) void k_qkv_gemm(const float* __restrict__ x,
                                                  const float* __restrict__ w,
                                                  float* __restrict__ qkv) {
  __shared__ unsigned short Ah[128][40];
  __shared__ unsigned short Al[128][40];
  __shared__ unsigned short Bh[128][40];
  __shared__ unsigned short Bl[128][40];

  const int b = blockIdx.z, o0 = blockIdx.y * 128, n0 = blockIdx.x * 128;
  const int t = threadIdx.x;
  const int lane = t & 63, wid = t >> 6;
  const int wr = wid >> 1, wc = wid & 1;
  const int frow = lane & 15;
  const int koff = (lane >> 4) * 8;

  f32x4 acc[4][4];
#pragma unroll
  for (int i = 0; i < 4; ++i)
#pragma unroll
    for (int j = 0; j < 4; ++j) acc[i][j] = (f32x4){0.f, 0.f, 0.f, 0.f};

  const float* wb = w + (size_t)o0 * CC;
  const float* xb = x + (size_t)b * NN * CC + (size_t)n0 * CC;

  for (int c0 = 0; c0 < CC; c0 += 32) {
    if (c0) __syncthreads();
#pragma unroll
    for (int r = 0; r < 4; ++r) {
      int idx = t + 256 * r;
      int row = idx >> 3, c4 = idx & 7;
      float4 va = *(const float4*)(wb + (size_t)row * CC + c0 + c4 * 4);
      float4 vb = *(const float4*)(xb + (size_t)row * CC + c0 + c4 * 4);
      float af[4] = {va.x, va.y, va.z, va.w};
      float bf[4] = {vb.x, vb.y, vb.z, vb.w};
      unsigned short ah4[4], al4[4], bh4[4], bl4[4];
#pragma unroll
      for (int e = 0; e < 4; ++e) {
        unsigned ua = __float_as_uint(af[e]);
        unsigned short ha = (unsigned short)(ua >> 16);
        ah4[e] = ha;
        al4[e] = f2bf_rne(af[e] - bf2f(ha));
        unsigned ub = __float_as_uint(bf[e]);
        unsigned short hb = (unsigned short)(ub >> 16);
        bh4[e] = hb;
        bl4[e] = f2bf_rne(bf[e] - bf2f(hb));
      }
      *(short4*)&Ah[row][c4 * 4] = make_short4(ah4[0], ah4[1], ah4[2], ah4[3]);
      *(short4*)&Al[row][c4 * 4] = make_short4(al4[0], al4[1], al4[2], al4[3]);
      *(short4*)&Bh[row][c4 * 4] = make_short4(bh4[0], bh4[1], bh4[2], bh4[3]);
      *(short4*)&Bl[row][c4 * 4] = make_short4(bl4[0], bl4[1], bl4[2], bl4[3]);
    }
    __syncthreads();

    bf16x8 fah[4], fal[4], fbh[4], fbl[4];
#pragma unroll
    for (int mi = 0; mi < 4; ++mi) {
      int rr = wr * 64 + mi * 16 + frow;
      fah[mi] = *(const bf16x8*)&Ah[rr][koff];
      fal[mi] = *(const bf16x8*)&Al[rr][koff];
    }
#pragma unroll
    for (int nj = 0; nj < 4; ++nj) {
      int rr = wc * 64 + nj * 16 + frow;
      fbh[nj] = *(const bf16x8*)&Bh[rr][koff];
      fbl[nj] = *(const bf16x8*)&Bl[rr][koff];
    }
#pragma unroll
    for (int mi = 0; mi < 4; ++mi)
#pragma unroll
      for (int nj = 0; nj < 4; ++nj) {
        acc[mi][nj] = __builtin_amdgcn_mfma_f32_16x16x32_bf16(fah[mi], fbh[nj], acc[mi][nj], 0, 0, 0);
        acc[mi][nj] = __builtin_amdgcn_mfma_f32_16x16x32_bf16(fah[mi], fbl[nj], acc[mi][nj], 0, 0, 0);
        acc[mi][nj] = __builtin_amdgcn_mfma_f32_16x16x32_bf16(fal[mi], fbh[nj], acc[mi][nj], 0, 0, 0);
      }
  }

#pragma unroll
  for (int mi = 0; mi < 4; ++mi) {
    int orow = o0 + wr * 64 + mi * 16 + (lane >> 4) * 4;
#pragma unroll
    for (int nj = 0; nj < 4; ++nj) {
      int ncol = n0 + wc * 64 + nj * 16 + frow;
      float* dst = qkv + ((size_t)b * OO + orow) * NN + ncol;
#pragma unroll
      for (int j = 0; j < 4; ++j) dst[(size_t)j * NN] = acc[mi][nj][j];
    }
  }
}

// ---------------- K2: per-channel BN scale/shift for qkv ----------------
__global__ __launch_bounds__(256) void k_qkv_stats(const float* __restrict__ qkv,
                                                   const float* __restrict__ gq,
                                                   const float* __restrict__ bq,
                                                   float* __restrict__ qs,
                                                   float* __restrict__ qh) {
  const int o = blockIdx.x;
  const int t = threadIdx.x;
  float s = 0.f, ss = 0.f;
  for (int b = 0; b < BB; ++b) {
    float v = qkv[((size_t)b * OO + o) * NN + t];
    s += v; ss += v * v;
  }
#pragma unroll
  for (int m = 1; m < 64; m <<= 1) { s += __shfl_xor(s, m); ss += __shfl_xor(ss, m); }
  __shared__ float rs[4], rss[4];
  int wv = t >> 6;
  if ((t & 63) == 0) { rs[wv] = s; rss[wv] = ss; }
  __syncthreads();
  if (t == 0) {
    s = rs[0] + rs[1] + rs[2] + rs[3];
    ss = rss[0] + rss[1] + rss[2] + rss[3];
    const float inv = 1.f / (float)(BB * NN);
    float m = s * inv;
    float var = ss * inv - m * m;
    float r = rsqrtf(var + 1e-5f);
    float sc = gq[o] * r;
    qs[o] = sc;
    qh[o] = bq[o] - m * sc;
  }
}

// ---------------- K3: pass1-lite — qr/kr BN stats via MFMA band-sums ----------
// ss_qr = sum_i sum_{u in [i,i+255]} Mq[i,u]^2,  Mq[i,u] = sum_c q_c(i) r_c(u)
// ss_kr analogous with k and r' (full window per j, no transpose needed).
#define P1_QH 0
#define P1_QL 5120
#define P1_KH 10240
#define P1_KL 15360
#define P1_RQ 20480
#define P1_RK 46080
#define P1_LDS 71680
#define QP 80

__global__ __launch_bounds__(512) void k_p1lite(const float* __restrict__ qkv,
                                                const float* __restrict__ relp,
                                                const float* __restrict__ qs,
                                                const float* __restrict__ qh,
                                                float* __restrict__ simacc) {
  extern __shared__ char lds[];
  const int it = blockIdx.x, bg = blockIdx.y;
  const int b = bg >> 3, g = bg & 7, i0 = it * 64;
  const int t = threadIdx.x, lane = t & 63, wid = t >> 6;
  const int cg = lane & 15, hi = lane >> 4;
  const int wi = wid & 3, wj = wid >> 2;

  // ---- stage Q rows iL, cols c (BN, hi/lo) ----
  {
    int c = t >> 4;
    int o = g * 128 + c;
    float sc = qs[o], hh = qh[o];
    int i4 = (t & 15) * 4;
    float4 v = *(const float4*)(qkv + ((size_t)b * OO + o) * NN + i0 + i4);
    float vv[4] = {v.x * sc + hh, v.y * sc + hh, v.z * sc + hh, v.w * sc + hh};
#pragma unroll
    for (int e = 0; e < 4; ++e) {
      unsigned short hb = (unsigned short)(__float_as_uint(vv[e]) >> 16);
      *(unsigned short*)(lds + P1_QH + (i4 + e) * QP + c * 2) = hb;
      *(unsigned short*)(lds + P1_QL + (i4 + e) * QP + c * 2) = f2bf_rne(vv[e] - bf2f(hb));
    }
  }
  // ---- stage K rows jL (window i0), cols c (BN, hi/lo) ----
  {
    int c = t >> 4;
    int o = g * 128 + 32 + c;
    float sc = qs[o], hh = qh[o];
    int i4 = (t & 15) * 4;
    float4 v = *(const float4*)(qkv + ((size_t)b * OO + o) * NN + i0 + i4);
    float vv[4] = {v.x * sc + hh, v.y * sc + hh, v.z * sc + hh, v.w * sc + hh};
#pragma unroll
    for (int e = 0; e < 4; ++e) {
      unsigned short hb = (unsigned short)(__float_as_uint(vv[e]) >> 16);
      *(unsigned short*)(lds + P1_KH + (i4 + e) * QP + c * 2) = hb;
      *(unsigned short*)(lds + P1_KL + (i4 + e) * QP + c * 2) = f2bf_rne(vv[e] - bf2f(hb));
    }
  }
  // ---- stage Rq[u][c] = relp[c][i0+u], Rk[v][c] = relp[32+c][i0+v], u,v<320 ----
  {
    int c = t >> 4;
    const float* sq = relp + c * 512 + i0;
    const float* sk = relp + (32 + c) * 512 + i0;
#pragma unroll
    for (int r = 0; r < 5; ++r) {
      int u4 = ((t & 15) + 16 * r) * 4;
      float4 vq = *(const float4*)(sq + u4);
      float4 vk = *(const float4*)(sk + u4);
      float aq[4] = {vq.x, vq.y, vq.z, vq.w};
      float ak[4] = {vk.x, vk.y, vk.z, vk.w};
#pragma unroll
      for (int e = 0; e < 4; ++e) {
        *(unsigned short*)(lds + P1_RQ + (u4 + e) * QP + c * 2) = f2bf_rne(aq[e]);
        *(unsigned short*)(lds + P1_RK + (u4 + e) * QP + c * 2) = f2bf_rne(ak[e]);
      }
    }
  }
  __syncthreads();

  float s_qr = 0.f, ss_qr = 0.f, s_kr = 0.f, ss_kr = 0.f;
  const int arow = wi * 16 + cg;
  bf16x8 qhf = *(const bf16x8*)(lds + P1_QH + arow * QP + hi * 16);
  bf16x8 qlf = *(const bf16x8*)(lds + P1_QL + arow * QP + hi * 16);
  bf16x8 khf = *(const bf16x8*)(lds + P1_KH + arow * QP + hi * 16);
  bf16x8 klf = *(const bf16x8*)(lds + P1_KL + arow * QP + hi * 16);

#pragma unroll
  for (int m5 = 0; m5 < 10; ++m5) {
    int ntq = wj * 10 + m5;
    int brow = ntq * 16 + cg;
    bf16x8 rqf = *(const bf16x8*)(lds + P1_RQ + brow * QP + hi * 16);
    f32x4 mq = (f32x4){0.f, 0.f, 0.f, 0.f};
    mq = __builtin_amdgcn_mfma_f32_16x16x32_bf16(qhf, rqf, mq, 0, 0, 0);
    mq = __builtin_amdgcn_mfma_f32_16x16x32_bf16(qlf, rqf, mq, 0, 0, 0);
    bf16x8 rkf = *(const bf16x8*)(lds + P1_RK + brow * QP + hi * 16);
    f32x4 mk = (f32x4){0.f, 0.f, 0.f, 0.f};
    mk = __builtin_amdgcn_mfma_f32_16x16x32_bf16(khf, rkf, mk, 0, 0, 0);
    mk = __builtin_amdgcn_mfma_f32_16x16x32_bf16(klf, rkf, mk, 0, 0, 0);
#pragma unroll
    for (int e = 0; e < 4; ++e) {
      int rowL = wi * 16 + hi * 4 + e;
      int u = ntq * 16 + cg;
      if ((unsigned)(u - rowL) < 256u) {
        s_qr += mq[e]; ss_qr += mq[e] * mq[e];
        s_kr += mk[e]; ss_kr += mk[e] * mk[e];
      }
    }
  }

#pragma unroll
  for (int m = 1; m < 64; m <<= 1) {
    s_qr += __shfl_xor(s_qr, m);
    ss_qr += __shfl_xor(ss_qr, m);
    s_kr += __shfl_xor(s_kr, m);
    ss_kr += __shfl_xor(ss_kr, m);
  }
  if (lane == 0) {
    atomicAdd(&simacc[8 + g], s_qr * F_QR);
    atomicAdd(&simacc[16 + g], s_kr * F_KR);
    atomicAdd(&simacc[24 + 8 + g], ss_qr * (F_QR * F_QR));
    atomicAdd(&simacc[24 + 16 + g], ss_kr * (F_KR * F_KR));
  }
}

// ---------------- K3c: qk BN stats via Grams: ss_qk = <Gq, Gk> ----------------
#define GQC 0
#define GKC 16896
#define GGQ 33792
#define GGK 38016

__global__ __launch_bounds__(256) void k_gram(const float* __restrict__ qkv,
                                              const float* __restrict__ qs,
                                              const float* __restrict__ qh,
                                              float* __restrict__ simacc) {
  __shared__ char gsh[42240];
  __shared__ float r1[4], r2[4];
  const int b = blockIdx.x >> 3, g = blockIdx.x & 7;
  const int t = threadIdx.x, lane = t & 63, wid = t >> 6;
  const int cg = lane & 15, hi = lane >> 4;

  // stage Qc[c][i], Kc[c][i] bf16, pitch 528B
  {
    int c = t >> 3, ch = (t & 7) * 32;
    int oq = g * 128 + c, ok = oq + 32;
    float sq = qs[oq], hq = qh[oq], sk = qs[ok], hk = qh[ok];
    const float* srq = qkv + ((size_t)b * OO + oq) * NN + ch;
    const float* srk = qkv + ((size_t)b * OO + ok) * NN + ch;
#pragma unroll
    for (int r = 0; r < 8; ++r) {
      float4 vq = *(const float4*)(srq + r * 4);
      float4 vk = *(const float4*)(srk + r * 4);
      short4 s4q = make_short4(f2bf_rne(vq.x * sq + hq), f2bf_rne(vq.y * sq + hq),
                               f2bf_rne(vq.z * sq + hq), f2bf_rne(vq.w * sq + hq));
      short4 s4k = make_short4(f2bf_rne(vk.x * sk + hk), f2bf_rne(vk.y * sk + hk),
                               f2bf_rne(vk.z * sk + hk), f2bf_rne(vk.w * sk + hk));
      *(short4*)(gsh + GQC + c * 528 + (ch + r * 4) * 2) = s4q;
      *(short4*)(gsh + GKC + c * 528 + (ch + r * 4) * 2) = s4k;
    }
  }
  __syncthreads();

  // Gram MFMA: waves 0-1 -> Gq row-tiles 0/1; waves 2-3 -> Gk
  {
    int base = (wid >> 1) ? GKC : GQC;
    int gbase = (wid >> 1) ? GGK : GGQ;
    int rt = wid & 1;
    f32x4 acc0 = (f32x4){0.f, 0.f, 0.f, 0.f};
    f32x4 acc1 = (f32x4){0.f, 0.f, 0.f, 0.f};
#pragma unroll
    for (int ks = 0; ks < 8; ++ks) {
      bf16x8 af = *(const bf16x8*)(gsh + base + (rt * 16 + cg) * 528 + ks * 64 + hi * 16);
      bf16x8 b0 = *(const bf16x8*)(gsh + base + (cg) * 528 + ks * 64 + hi * 16);
      bf16x8 b1 = *(const bf16x8*)(gsh + base + (16 + cg) * 528 + ks * 64 + hi * 16);
      acc0 = __builtin_amdgcn_mfma_f32_16x16x32_bf16(af, b0, acc0, 0, 0, 0);
      acc1 = __builtin_amdgcn_mfma_f32_16x16x32_bf16(af, b1, acc1, 0, 0, 0);
    }
#pragma unroll
    for (int e = 0; e < 4; ++e) {
      int row = rt * 16 + hi * 4 + e;
      *(float*)(gsh + gbase + (row * 33 + cg) * 4) = acc0[e];
      *(float*)(gsh + gbase + (row * 33 + 16 + cg) * 4) = acc1[e];
    }
  }
  __syncthreads();

  float ssqk = 0.f;
#pragma unroll
  for (int pp = 0; pp < 4; ++pp) {
    int p = t * 4 + pp;
    int c = p >> 5, cp = p & 31;
    float gq = *(const float*)(gsh + GGQ + (c * 33 + cp) * 4);
    float gk = *(const float*)(gsh + GGK + (c * 33 + cp) * 4);
    ssqk += gq * gk;
  }
  // column sums for means
  float sq = 0.f, sk = 0.f;
  {
    int c = t >> 3, ch = (t & 7) * 32;
#pragma unroll 8
    for (int r = 0; r < 32; ++r) {
      sq += bf2f(*(const unsigned short*)(gsh + GQC + c * 528 + (ch + r) * 2));
      sk += bf2f(*(const unsigned short*)(gsh + GKC + c * 528 + (ch + r) * 2));
    }
  }
#pragma unroll
  for (int m = 1; m < 8; m <<= 1) { sq += __shfl_xor(sq, m); sk += __shfl_xor(sk, m); }
  float sprod = ((t & 7) == 0) ? sq * sk : 0.f;
#pragma unroll
  for (int m = 1; m < 64; m <<= 1) { ssqk += __shfl_xor(ssqk, m); sprod += __shfl_xor(sprod, m); }
  if (lane == 0) { r1[wid] = ssqk; r2[wid] = sprod; }
  __syncthreads();
  if (t == 0) {
    atomicAdd(&simacc[24 + g], r1[0] + r1[1] + r1[2] + r1[3]);
    atomicAdd(&simacc[g], r2[0] + r2[1] + r2[2] + r2[3]);
  }
}

// ---------------- finalize sim BN coefficients ----------------
__global__ void k_sim_finalize(const float* __restrict__ simacc,
                               const float* __restrict__ gs,
                               const float* __restrict__ bs,
                               float* __restrict__ simscale,
                               float* __restrict__ simshift) {
  const int t = threadIdx.x;
  __shared__ float sh[24];
  if (t < 24) {
    const float inv = 1.f / (64.f * 256.f * 256.f);
    float m = simacc[t] * inv;
    float var = simacc[24 + t] * inv - m * m;
    float a = gs[t] * rsqrtf(var + 1e-5f);
    simscale[t] = a;
    sh[t] = bs[t] - m * a;
  }
  __syncthreads();
  if (t < 8) simshift[t] = sh[t] + sh[8 + t] + sh[16 + t];
}

// ---------------- pass2: all-MFMA, 8 waves, pitched LDS (unchanged r7) -------
#define MG_OFF   0
#define SMX_OFF  0
#define SMS_OFF  512
#define KH_OFF   45056
#define KL_OFF   65536
#define RST_OFF  86016
#define QH_OFF   111616
#define QL_OFF   116736
#define VB_OFF   45056
#define PF_OFF   86016
#define RV_OFF   121856
#define P2_LDS   163840
#define MQP 656
#define GP  176
#define PFP 528
#define RVP 656

__global__ __launch_bounds__(512) void k_pass2(const float* __restrict__ qkv,
                                               const float* __restrict__ relp,
                                               const float* __restrict__ qs,
                                               const float* __restrict__ qh,
                                               const float* __restrict__ simscale,
                                               float* __restrict__ svbuf,
                                               float* __restrict__ svebuf) {
  extern __shared__ char lds[];
  const int it = blockIdx.x, bg = blockIdx.y;
  const int b = bg >> 3, g = bg & 7, i0 = it * 64;
  const int t = threadIdx.x, lane = t & 63, wid = t >> 6;
  const int cg = lane & 15, hi = lane >> 4;
  const int wi = wid & 3, wj = wid >> 2;
  const float aQK = simscale[g];
  const float aQR = F_QR * simscale[8 + g];
  const float aKR = F_KR * simscale[16 + g];

  {
    int c = t >> 4;
    int o = g * 128 + c;
    float sc = qs[o], hh = qh[o];
    int i4 = (t & 15) * 4;
    float4 v = *(const float4*)(qkv + ((size_t)b * OO + o) * NN + i0 + i4);
    float vv[4] = {v.x * sc + hh, v.y * sc + hh, v.z * sc + hh, v.w * sc + hh};
#pragma unroll
    for (int e = 0; e < 4; ++e) {
      int iL = i4 + e;
      unsigned short hb = (unsigned short)(__float_as_uint(vv[e]) >> 16);
      *(unsigned short*)(lds + QH_OFF + iL * QP + c * 2) = hb;
      *(unsigned short*)(lds + QL_OFF + iL * QP + c * 2) = f2bf_rne(vv[e] - bf2f(hb));
    }
  }
  {
    int c = t >> 4;
    int o = g * 128 + 32 + c;
    float sc = qs[o], hh = qh[o];
    const float* src = qkv + ((size_t)b * OO + o) * NN;
#pragma unroll
    for (int r = 0; r < 4; ++r) {
      int j4 = ((t & 15) + 16 * r) * 4;
      float4 v = *(const float4*)(src + j4);
      float vv[4] = {v.x * sc + hh, v.y * sc + hh, v.z * sc + hh, v.w * sc + hh};
#pragma unroll
      for (int e = 0; e < 4; ++e) {
        int j = j4 + e;
        unsigned short hb = (unsigned short)(__float_as_uint(vv[e]) >> 16);
        *(unsigned short*)(lds + KH_OFF + j * QP + c * 2) = hb;
        *(unsigned short*)(lds + KL_OFF + j * QP + c * 2) = f2bf_rne(vv[e] - bf2f(hb));
      }
    }
  }
  {
    int c = t >> 4;
    const float* src = relp + c * 512 + i0;
#pragma unroll
    for (int r = 0; r < 5; ++r) {
      int u4 = ((t & 15) + 16 * r) * 4;
      float4 v = *(const float4*)(src + u4);
      float vv[4] = {v.x, v.y, v.z, v.w};
#pragma unroll
      for (int e = 0; e < 4; ++e)
        *(unsigned short*)(lds + RST_OFF + (u4 + e) * QP + c * 2) = f2bf_rne(vv[e]);
    }
  }
  __syncthreads();

  f32x4 p[8];
#pragma unroll
  for (int n = 0; n < 8; ++n) p[n] = (f32x4){0.f, 0.f, 0.f, 0.f};

  int qrow = wi * 16 + cg;
  bf16x8 qhf = *(const bf16x8*)(lds + QH_OFF + qrow * QP + hi * 16);
  bf16x8 qlf = *(const bf16x8*)(lds + QL_OFF + qrow * QP + hi * 16);
#pragma unroll
  for (int n = 0; n < 8; ++n) {
    int krow = (wj * 8 + n) * 16 + cg;
    bf16x8 khf = *(const bf16x8*)(lds + KH_OFF + krow * QP + hi * 16);
    bf16x8 klf = *(const bf16x8*)(lds + KL_OFF + krow * QP + hi * 16);
    p[n] = __builtin_amdgcn_mfma_f32_16x16x32_bf16(qhf, khf, p[n], 0, 0, 0);
    p[n] = __builtin_amdgcn_mfma_f32_16x16x32_bf16(qhf, klf, p[n], 0, 0, 0);
    p[n] = __builtin_amdgcn_mfma_f32_16x16x32_bf16(qlf, khf, p[n], 0, 0, 0);
  }
#pragma unroll
  for (int n = 0; n < 8; ++n)
#pragma unroll
    for (int e = 0; e < 4; ++e) p[n][e] *= aQK;

#pragma unroll
  for (int m5 = 0; m5 < 10; ++m5) {
    int ntq = wj * 10 + m5;
    bf16x8 rf = *(const bf16x8*)(lds + RST_OFF + (ntq * 16 + cg) * QP + hi * 16);
    f32x4 m = (f32x4){0.f, 0.f, 0.f, 0.f};
    m = __builtin_amdgcn_mfma_f32_16x16x32_bf16(qhf, rf, m, 0, 0, 0);
#pragma unroll
    for (int e = 0; e < 4; ++e) {
      int iL = wi * 16 + hi * 4 + e;
      *(unsigned short*)(lds + MG_OFF + iL * MQP + (ntq * 16 + cg) * 2) = f2bf_rne(m[e]);
    }
  }
  __syncthreads();

#pragma unroll
  for (int n = 0; n < 8; ++n)
#pragma unroll
    for (int e = 0; e < 4; ++e) {
      int iL = wi * 16 + hi * 4 + e;
      int ul = iL - ((wj * 8 + n) * 16 + cg) + 255;
      p[n][e] += aQR * bf2f(*(const unsigned short*)(lds + MG_OFF + iL * MQP + ul * 2));
    }
  {
    int c = t >> 4;
    const float* src = relp + (32 + c) * 512 + (192 - i0);
#pragma unroll
    for (int r = 0; r < 5; ++r) {
      int u4 = ((t & 15) + 16 * r) * 4;
      float4 v = *(const float4*)(src + u4);
      float vv[4] = {v.x, v.y, v.z, v.w};
#pragma unroll
      for (int e = 0; e < 4; ++e)
        *(unsigned short*)(lds + RST_OFF + (u4 + e) * QP + c * 2) = f2bf_rne(vv[e]);
    }
  }
  __syncthreads();

#pragma unroll
  for (int jj = 0; jj < 2; ++jj) {
    int jt = wid * 2 + jj;
    bf16x8 kf = *(const bf16x8*)(lds + KH_OFF + (jt * 16 + cg) * QP + hi * 16);
#pragma unroll
    for (int n5 = 0; n5 < 5; ++n5) {
      bf16x8 rf = *(const bf16x8*)(lds + RST_OFF + ((jt + n5) * 16 + cg) * QP + hi * 16);
      f32x4 gacc = (f32x4){0.f, 0.f, 0.f, 0.f};
      gacc = __builtin_amdgcn_mfma_f32_16x16x32_bf16(kf, rf, gacc, 0, 0, 0);
#pragma unroll
      for (int e = 0; e < 4; ++e) {
        int j = jt * 16 + hi * 4 + e;
        *(unsigned short*)(lds + MG_OFF + j * GP + (n5 * 16 + cg) * 2) = f2bf_rne(gacc[e]);
      }
    }
  }
  __syncthreads();

#pragma unroll
  for (int n = 0; n < 8; ++n)
#pragma unroll
    for (int e = 0; e < 4; ++e) {
      int iL = wi * 16 + hi * 4 + e;
      int j = (wj * 8 + n) * 16 + cg;
      int sl = cg + 63 - iL;
      p[n][e] += aKR * bf2f(*(const unsigned short*)(lds + MG_OFF + j * GP + sl * 2));
    }
  __syncthreads();

  {
    float mloc[4];
#pragma unroll
    for (int e = 0; e < 4; ++e) {
      float m = p[0][e];
#pragma unroll
      for (int n = 1; n < 8; ++n) m = fmaxf(m, p[n][e]);
#pragma unroll
      for (int k = 1; k < 16; k <<= 1) m = fmaxf(m, __shfl_xor(m, k));
      mloc[e] = m;
    }
    if (cg == 0) {
#pragma unroll
      for (int e = 0; e < 4; ++e)
        *(float*)(lds + SMX_OFF + (wj * 64 + wi * 16 + hi * 4 + e) * 4) = mloc[e];
    }
    __syncthreads();
    float sloc[4];
#pragma unroll
    for (int e = 0; e < 4; ++e) {
      int iL = wi * 16 + hi * 4 + e;
      float m = fmaxf(*(const float*)(lds + SMX_OFF + iL * 4),
                      *(const float*)(lds + SMX_OFF + (64 + iL) * 4));
      float s = 0.f;
#pragma unroll
      for (int n = 0; n < 8; ++n) { float ev = __expf(p[n][e] - m); p[n][e] = ev; s += ev; }
#pragma unroll
      for (int k = 1; k < 16; k <<= 1) s += __shfl_xor(s, k);
      sloc[e] = s;
    }
    if (cg == 0) {
#pragma unroll
      for (int e = 0; e < 4; ++e)
        *(float*)(lds + SMS_OFF + (wj * 64 + wi * 16 + hi * 4 + e) * 4) = sloc[e];
    }
    __syncthreads();
#pragma unroll
    for (int e = 0; e < 4; ++e) {
      int iL = wi * 16 + hi * 4 + e;
      float s = *(const float*)(lds + SMS_OFF + iL * 4) +
                *(const float*)(lds + SMS_OFF + (64 + iL) * 4);
      float inv = 1.f / s;
#pragma unroll
      for (int n = 0; n < 8; ++n) p[n][e] *= inv;
    }
  }
  __syncthreads();

#pragma unroll
  for (int r = 0; r < 6; ++r) {
    int idx = r * 512 + t;
    if (idx < 2816) *(float4*)(lds + idx * 16) = make_float4(0.f, 0.f, 0.f, 0.f);
  }
  __syncthreads();

#pragma unroll
  for (int n = 0; n < 8; ++n)
#pragma unroll
    for (int e = 0; e < 4; ++e) {
      int iL = wi * 16 + hi * 4 + e;
      int j = (wj * 8 + n) * 16 + cg;
      unsigned short hv = f2bf_rne(p[n][e]);
      *(unsigned short*)(lds + PF_OFF + iL * PFP + j * 2) = hv;
      int us = iL + 255 - j;
      *(unsigned short*)(lds + MG_OFF + iL * MQP + us * 2) = hv;
    }
  {
    int cp = (t >> 2) & 63, half = t >> 8;
    int o = g * 128 + 64 + cp;
    float sc = qs[o], hh = qh[o];
    const float* src = qkv + ((size_t)b * OO + o) * NN;
#pragma unroll
    for (int r = 0; r < 8; ++r) {
      int ch = (t & 3) + half * 4 + 8 * r;
      float4 v = *(const float4*)(src + ch * 4);
      short4 s4 = make_short4(f2bf_rne(v.x * sc + hh), f2bf_rne(v.y * sc + hh),
                              f2bf_rne(v.z * sc + hh), f2bf_rne(v.w * sc + hh));
      *(short4*)(lds + VB_OFF + cp * PFP + ch * 8) = s4;
    }
    const float* srv = relp + (size_t)(64 + cp) * 512 + i0;
#pragma unroll
    for (int r = 0; r < 10; ++r) {
      int ch = (t & 3) + half * 4 + 8 * r;
      float4 v = *(const float4*)(srv + ch * 4);
      short4 s4 = make_short4(f2bf_rne(v.x), f2bf_rne(v.y), f2bf_rne(v.z), f2bf_rne(v.w));
      *(short4*)(lds + RV_OFF + cp * RVP + ch * 8) = s4;
    }
  }
  __syncthreads();

  {
    int prow = wi * 16 + cg;
    bf16x8 af[8];
#pragma unroll
    for (int ks = 0; ks < 8; ++ks)
      af[ks] = *(const bf16x8*)(lds + PF_OFF + prow * PFP + ks * 64 + hi * 16);
#pragma unroll
    for (int n = 0; n < 2; ++n) {
      int ntv = wj * 2 + n;
      f32x4 acc = (f32x4){0.f, 0.f, 0.f, 0.f};
#pragma unroll
      for (int ks = 0; ks < 8; ++ks) {
        bf16x8 bfv = *(const bf16x8*)(lds + VB_OFF + (ntv * 16 + cg) * PFP + ks * 64 + hi * 16);
        acc = __builtin_amdgcn_mfma_f32_16x16x32_bf16(af[ks], bfv, acc, 0, 0, 0);
      }
      float* dst = svbuf + ((size_t)(b * 512 + g * 64 + ntv * 16 + cg)) * NN + i0 + wi * 16 + hi * 4;
      *(float4*)dst = make_float4(acc[0], acc[1], acc[2], acc[3]);
    }
    bf16x8 ae[10];
#pragma unroll
    for (int ks = 0; ks < 10; ++ks)
      ae[ks] = *(const bf16x8*)(lds + MG_OFF + prow * MQP + ks * 64 + hi * 16);
#pragma unroll
    for (int n = 0; n < 2; ++n) {
      int ntv = wj * 2 + n;
      f32x4 acc = (f32x4){0.f, 0.f, 0.f, 0.f};
#pragma unroll
      for (int ks = 0; ks < 10; ++ks) {
        bf16x8 bfr = *(const bf16x8*)(lds + RV_OFF + (ntv * 16 + cg) * RVP + ks * 64 + hi * 16);
        acc = __builtin_amdgcn_mfma_f32_16x16x32_bf16(ae[ks], bfr, acc, 0, 0, 0);
      }
      float* dst = svebuf + ((size_t)(b * 512 + g * 64 + ntv * 16 + cg)) * NN + i0 + wi * 16 + hi * 4;
      *(float4*)dst = make_float4(acc[0] * F_SVE, acc[1] * F_SVE, acc[2] * F_SVE, acc[3] * F_SVE);
    }
  }
}

// ---------------- K6: final BN stats over sv / sve ----------------
__global__ __launch_bounds__(256) void k_out_stats(const float* __restrict__ svbuf,
                                                   const float* __restrict__ svebuf,
                                                   const float* __restrict__ go,
                                                   const float* __restrict__ bo,
                                                   float* __restrict__ osc,
                                                   float* __restrict__ osh) {
  const int bid = blockIdx.x;
  const int arr = bid >> 9, pch = bid & 511;
  const float* buf = arr ? svebuf : svbuf;
  const int t = threadIdx.x;
  float s = 0.f, ss = 0.f;
  for (int b = 0; b < BB; ++b) {
    float v = buf[((size_t)b * 512 + pch) * NN + t];
    s += v; ss += v * v;
  }
#pragma unroll
  for (int m = 1; m < 64; m <<= 1) { s += __shfl_xor(s, m); ss += __shfl_xor(ss, m); }
  __shared__ float rs[4], rss[4];
  int wv = t >> 6;
  if ((t & 63) == 0) { rs[wv] = s; rss[wv] = ss; }
  __syncthreads();
  if (t == 0) {
    s = rs[0] + rs[1] + rs[2] + rs[3];
    ss = rss[0] + rss[1] + rss[2] + rss[3];
    const float inv = 1.f / 16384.f;
    float m = s * inv;
    float var = ss * inv - m * m;
    float r = rsqrtf(var + 1e-5f);
    int o = pch * 2 + arr;
    float sc = go[o] * r;
    osc[bid] = sc;
    osh[bid] = bo[o] - m * sc;
  }
}

// ---------------- K7: combine ----------------
__global__ __launch_bounds__(256) void k_final(const float* __restrict__ svbuf,
                                               const float* __restrict__ svebuf,
                                               const float* __restrict__ osc,
                                               const float* __restrict__ osh,
                                               float* __restrict__ out) {
  const size_t f = (size_t)blockIdx.x * 256 + threadIdx.x;
  const int pch = (int)((f >> 6) & 511);
  float4 a = ((const float4*)svbuf)[f];
  float4 e = ((const float4*)svebuf)[f];
  float s1 = osc[pch], h1 = osh[pch];
  float s2 = osc[512 + pch], h2 = osh[512 + pch];
  float hh = h1 + h2;
  float4 o;
  o.x = a.x * s1 + e.x * s2 + hh;
  o.y = a.y * s1 + e.y * s2 + hh;
  o.z = a.z * s1 + e.z * s2 + hh;
  o.w = a.w * s1 + e.w * s2 + hh;
  ((float4*)out)[f] = o;
}

extern "C" void kernel_launch(void* const* d_in, const int* in_sizes, int n_in,
                              void* d_out, int out_size, void* d_ws, size_t ws_size,
                              hipStream_t stream) {
  const float* x     = (const float*)d_in[0];
  const float* w     = (const float*)d_in[1];
  const float* rel   = (const float*)d_in[2];
  const float* g_qkv = (const float*)d_in[3];
  const float* b_qkv = (const float*)d_in[4];
  const float* g_sim = (const float*)d_in[5];
  const float* b_sim = (const float*)d_in[6];
  const float* g_out = (const float*)d_in[7];
  const float* b_out = (const float*)d_in[8];

  float* ws = (float*)d_ws;
  float* qkv      = ws;
  float* sv       = qkv + 16777216;
  float* sve      = sv + 8388608;
  float* qs       = sve + 8388608;
  float* qh       = qs + 1024;
  float* simacc   = qh + 1024;
  float* simscale = simacc + 48;
  float* simshift = simscale + 24;
  float* osc      = simshift + 8;
  float* osh      = osc + 1024;

  float* relp = (float*)d_out;

  hipFuncSetAttribute((const void*)k_pass2, hipFuncAttributeMaxDynamicSharedMemorySize, P2_LDS);
  hipFuncSetAttribute((const void*)k_p1lite, hipFuncAttributeMaxDynamicSharedMemorySize, P1_LDS);

  hipMemsetAsync(simacc, 0, 48 * sizeof(float), stream);

  k_relpad<<<128, 256, 0, stream>>>(rel, relp);
  k_qkv_gemm<<<dim3(2, 8, 64), 256, 0, stream>>>(x, w, qkv);
  k_qkv_stats<<<1024, 256, 0, stream>>>(qkv, g_qkv, b_qkv, qs, qh);
  k_p1lite<<<dim3(4, 512), 512, P1_LDS, stream>>>(qkv, relp, qs, qh, simacc);
  k_gram<<<512, 256, 0, stream>>>(qkv, qs, qh, simacc);
  k_sim_finalize<<<1, 32, 0, stream>>>(simacc, g_sim, b_sim, simscale, simshift);
  k_pass2<<<dim3(4, 512), 512, P2_LDS, stream>>>(qkv, relp, qs, qh, simscale, sv, sve);
  k_out_stats<<<1024, 256, 0, stream>>>(sv, sve, g_out, b_out, osc, osh);
  k_final<<<8192, 256, 0, stream>>>(sv, sve, osc, osh, (float*)d_out);
}

// Round 10
// 413.967 us; speedup vs baseline: 2.0510x; 2.0510x over previous
//
#include <hip/hip_runtime.h>

#define NN 256
#define CC 512
#define OO 1024
#define BB 64

#define F_QR 0.1f
#define F_KR 0.1f
#define F_SVE 0.1f

typedef __attribute__((ext_vector_type(8))) short bf16x8;
typedef __attribute__((ext_vector_type(4))) float f32x4;

__device__ inline unsigned short f2bf_rne(float f) {
  unsigned u = __float_as_uint(f);
  u += 0x7fffu + ((u >> 16) & 1u);
  return (unsigned short)(u >> 16);
}

__device__ inline float bf2f(unsigned short h) {
  return __uint_as_float((unsigned)h << 16);
}

// ---------------- K0: pad rel rows 511 -> 512 ----------------
__global__ void k_relpad(const float* __restrict__ rel, float* __restrict__ relp) {
  const int row = blockIdx.x;
  const int t = threadIdx.x;
  for (int u = t; u < 511; u += 256) relp[row * 512 + u] = rel[row * 511 + u];
  if (t == 0) relp[row * 512 + 511] = 0.f;
}

// ---------------- K1: qkv GEMM (split-bf16 MFMA, verified round 5) ----------------
__global__ __launch_bounds__(256) void k_qkv_gemm(const float* __restrict__ x,
                                                  const float* __restrict__ w,
                                                  float* __restrict__ qkv) {
  __shared__ unsigned short Ah[128][40];
  __shared__ unsigned short Al[128][40];
  __shared__ unsigned short Bh[128][40];
  __shared__ unsigned short Bl[128][40];

  const int b = blockIdx.z, o0 = blockIdx.y * 128, n0 = blockIdx.x * 128;
  const int t = threadIdx.x;
  const int lane = t & 63, wid = t >> 6;
  const int wr = wid >> 1, wc = wid & 1;
  const int frow = lane & 15;
  const int koff = (lane >> 4) * 8;

  f32x4 acc[4][4];
#pragma unroll
  for (int i = 0; i < 4; ++i)
#pragma unroll
    for (int j = 0; j < 4; ++j) acc[i][j] = (f32x4){0.f, 0.f, 0.f, 0.f};

  const float* wb = w + (size_t)o0 * CC;
  const float* xb = x + (size_t)b * NN * CC + (size_t)n0 * CC;

  for (int c0 = 0; c0 < CC; c0 += 32) {
    if (c0) __syncthreads();
#pragma unroll
    for (int r = 0; r < 4; ++r) {
      int idx = t + 256 * r;
      int row = idx >> 3, c4 = idx & 7;
      float4 va = *(const float4*)(wb + (size_t)row * CC + c0 + c4 * 4);
      float4 vb = *(const float4*)(xb + (size_t)row * CC + c0 + c4 * 4);
      float af[4] = {va.x, va.y, va.z, va.w};
      float bf[4] = {vb.x, vb.y, vb.z, vb.w};
      unsigned short ah4[4], al4[4], bh4[4], bl4[4];
#pragma unroll
      for (int e = 0; e < 4; ++e) {
        unsigned ua = __float_as_uint(af[e]);
        unsigned short ha = (unsigned short)(ua >> 16);
        ah4[e] = ha;
        al4[e] = f2bf_rne(af[e] - bf2f(ha));
        unsigned ub = __float_as_uint(bf[e]);
        unsigned short hb = (unsigned short)(ub >> 16);
        bh4[e] = hb;
        bl4[e] = f2bf_rne(bf[e] - bf2f(hb));
      }
      *(short4*)&Ah[row][c4 * 4] = make_short4(ah4[0], ah4[1], ah4[2], ah4[3]);
      *(short4*)&Al[row][c4 * 4] = make_short4(al4[0], al4[1], al4[2], al4[3]);
      *(short4*)&Bh[row][c4 * 4] = make_short4(bh4[0], bh4[1], bh4[2], bh4[3]);
      *(short4*)&Bl[row][c4 * 4] = make_short4(bl4[0], bl4[1], bl4[2], bl4[3]);
    }
    __syncthreads();

    bf16x8 fah[4], fal[4], fbh[4], fbl[4];
#pragma unroll
    for (int mi = 0; mi < 4; ++mi) {
      int rr = wr * 64 + mi * 16 + frow;
      fah[mi] = *(const bf16x8*)&Ah[rr][koff];
      fal[mi] = *(const bf16x8*)&Al[rr][koff];
    }
#pragma unroll
    for (int nj = 0; nj < 4; ++nj) {
      int rr = wc * 64 + nj * 16 + frow;
      fbh[nj] = *(const bf16x8*)&Bh[rr][koff];
      fbl[nj] = *(const bf16x8*)&Bl[rr][koff];
    }
#pragma unroll
    for (int mi = 0; mi < 4; ++mi)
#pragma unroll
      for (int nj = 0; nj < 4; ++nj) {
        acc[mi][nj] = __builtin_amdgcn_mfma_f32_16x16x32_bf16(fah[mi], fbh[nj], acc[mi][nj], 0, 0, 0);
        acc[mi][nj] = __builtin_amdgcn_mfma_f32_16x16x32_bf16(fah[mi], fbl[nj], acc[mi][nj], 0, 0, 0);
        acc[mi][nj] = __builtin_amdgcn_mfma_f32_16x16x32_bf16(fal[mi], fbh[nj], acc[mi][nj], 0, 0, 0);
      }
  }

#pragma unroll
  for (int mi = 0; mi < 4; ++mi) {
    int orow = o0 + wr * 64 + mi * 16 + (lane >> 4) * 4;
#pragma unroll
    for (int nj = 0; nj < 4; ++nj) {
      int ncol = n0 + wc * 64 + nj * 16 + frow;
      float* dst = qkv + ((size_t)b * OO + orow) * NN + ncol;
#pragma unroll
      for (int j = 0; j < 4; ++j) dst[(size_t)j * NN] = acc[mi][nj][j];
    }
  }
}

// ---------------- K2: per-channel BN scale/shift for qkv ----------------
__global__ __launch_bounds__(256) void k_qkv_stats(const float* __restrict__ qkv,
                                                   const float* __restrict__ gq,
                                                   const float* __restrict__ bq,
                                                   float* __restrict__ qs,
                                                   float* __restrict__ qh) {
  const int o = blockIdx.x;
  const int t = threadIdx.x;
  float s = 0.f, ss = 0.f;
  for (int b = 0; b < BB; ++b) {
    float v = qkv[((size_t)b * OO + o) * NN + t];
    s += v; ss += v * v;
  }
#pragma unroll
  for (int m = 1; m < 64; m <<= 1) { s += __shfl_xor(s, m); ss += __shfl_xor(ss, m); }
  __shared__ float rs[4], rss[4];
  int wv = t >> 6;
  if ((t & 63) == 0) { rs[wv] = s; rss[wv] = ss; }
  __syncthreads();
  if (t == 0) {
    s = rs[0] + rs[1] + rs[2] + rs[3];
    ss = rss[0] + rss[1] + rss[2] + rss[3];
    const float inv = 1.f / (float)(BB * NN);
    float m = s * inv;
    float var = ss * inv - m * m;
    float r = rsqrtf(var + 1e-5f);
    float sc = gq[o] * r;
    qs[o] = sc;
    qh[o] = bq[o] - m * sc;
  }
}

// ---------------- K3: pass1-lite — qr/kr BN stats via MFMA band-sums ----------
// ss_qr = sum_i sum_{u in [i,i+255]} Mq[i,u]^2,  Mq[i,u] = sum_c q_c(i) r_c(u)
// NO ATOMICS: per-block partials to unique global slots (r9's 480us was a
// 2048-deep same-address device-atomic chain, ~235ns/op).
#define P1_QH 0
#define P1_QL 5120
#define P1_KH 10240
#define P1_KL 15360
#define P1_RQ 20480
#define P1_RK 46080
#define P1_LDS 71680
#define QP 80

__global__ __launch_bounds__(512) void k_p1lite(const float* __restrict__ qkv,
                                                const float* __restrict__ relp,
                                                const float* __restrict__ qs,
                                                const float* __restrict__ qh,
                                                float* __restrict__ p1part) {
  extern __shared__ char lds[];
  const int it = blockIdx.x, bg = blockIdx.y;
  const int b = bg >> 3, g = bg & 7, i0 = it * 64;
  const int t = threadIdx.x, lane = t & 63, wid = t >> 6;
  const int cg = lane & 15, hi = lane >> 4;
  const int wi = wid & 3, wj = wid >> 2;

  // ---- stage Q rows iL, cols c (BN, hi/lo) ----
  {
    int c = t >> 4;
    int o = g * 128 + c;
    float sc = qs[o], hh = qh[o];
    int i4 = (t & 15) * 4;
    float4 v = *(const float4*)(qkv + ((size_t)b * OO + o) * NN + i0 + i4);
    float vv[4] = {v.x * sc + hh, v.y * sc + hh, v.z * sc + hh, v.w * sc + hh};
#pragma unroll
    for (int e = 0; e < 4; ++e) {
      unsigned short hb = (unsigned short)(__float_as_uint(vv[e]) >> 16);
      *(unsigned short*)(lds + P1_QH + (i4 + e) * QP + c * 2) = hb;
      *(unsigned short*)(lds + P1_QL + (i4 + e) * QP + c * 2) = f2bf_rne(vv[e] - bf2f(hb));
    }
  }
  // ---- stage K rows jL (window i0), cols c (BN, hi/lo) ----
  {
    int c = t >> 4;
    int o = g * 128 + 32 + c;
    float sc = qs[o], hh = qh[o];
    int i4 = (t & 15) * 4;
    float4 v = *(const float4*)(qkv + ((size_t)b * OO + o) * NN + i0 + i4);
    float vv[4] = {v.x * sc + hh, v.y * sc + hh, v.z * sc + hh, v.w * sc + hh};
#pragma unroll
    for (int e = 0; e < 4; ++e) {
      unsigned short hb = (unsigned short)(__float_as_uint(vv[e]) >> 16);
      *(unsigned short*)(lds + P1_KH + (i4 + e) * QP + c * 2) = hb;
      *(unsigned short*)(lds + P1_KL + (i4 + e) * QP + c * 2) = f2bf_rne(vv[e] - bf2f(hb));
    }
  }
  // ---- stage Rq[u][c] = relp[c][i0+u], Rk[v][c] = relp[32+c][i0+v], u,v<320 ----
  {
    int c = t >> 4;
    const float* sq = relp + c * 512 + i0;
    const float* sk = relp + (32 + c) * 512 + i0;
#pragma unroll
    for (int r = 0; r < 5; ++r) {
      int u4 = ((t & 15) + 16 * r) * 4;
      float4 vq = *(const float4*)(sq + u4);
      float4 vk = *(const float4*)(sk + u4);
      float aq[4] = {vq.x, vq.y, vq.z, vq.w};
      float ak[4] = {vk.x, vk.y, vk.z, vk.w};
#pragma unroll
      for (int e = 0; e < 4; ++e) {
        *(unsigned short*)(lds + P1_RQ + (u4 + e) * QP + c * 2) = f2bf_rne(aq[e]);
        *(unsigned short*)(lds + P1_RK + (u4 + e) * QP + c * 2) = f2bf_rne(ak[e]);
      }
    }
  }
  __syncthreads();

  float s_qr = 0.f, ss_qr = 0.f, s_kr = 0.f, ss_kr = 0.f;
  const int arow = wi * 16 + cg;
  bf16x8 qhf = *(const bf16x8*)(lds + P1_QH + arow * QP + hi * 16);
  bf16x8 qlf = *(const bf16x8*)(lds + P1_QL + arow * QP + hi * 16);
  bf16x8 khf = *(const bf16x8*)(lds + P1_KH + arow * QP + hi * 16);
  bf16x8 klf = *(const bf16x8*)(lds + P1_KL + arow * QP + hi * 16);

#pragma unroll
  for (int m5 = 0; m5 < 10; ++m5) {
    int ntq = wj * 10 + m5;
    int brow = ntq * 16 + cg;
    bf16x8 rqf = *(const bf16x8*)(lds + P1_RQ + brow * QP + hi * 16);
    f32x4 mq = (f32x4){0.f, 0.f, 0.f, 0.f};
    mq = __builtin_amdgcn_mfma_f32_16x16x32_bf16(qhf, rqf, mq, 0, 0, 0);
    mq = __builtin_amdgcn_mfma_f32_16x16x32_bf16(qlf, rqf, mq, 0, 0, 0);
    bf16x8 rkf = *(const bf16x8*)(lds + P1_RK + brow * QP + hi * 16);
    f32x4 mk = (f32x4){0.f, 0.f, 0.f, 0.f};
    mk = __builtin_amdgcn_mfma_f32_16x16x32_bf16(khf, rkf, mk, 0, 0, 0);
    mk = __builtin_amdgcn_mfma_f32_16x16x32_bf16(klf, rkf, mk, 0, 0, 0);
#pragma unroll
    for (int e = 0; e < 4; ++e) {
      int rowL = wi * 16 + hi * 4 + e;
      int u = ntq * 16 + cg;
      if ((unsigned)(u - rowL) < 256u) {
        s_qr += mq[e]; ss_qr += mq[e] * mq[e];
        s_kr += mk[e]; ss_kr += mk[e] * mk[e];
      }
    }
  }

#pragma unroll
  for (int m = 1; m < 64; m <<= 1) {
    s_qr += __shfl_xor(s_qr, m);
    ss_qr += __shfl_xor(ss_qr, m);
    s_kr += __shfl_xor(s_kr, m);
    ss_kr += __shfl_xor(ss_kr, m);
  }
  // cross-wave reduce in (now dead) staging LDS, single global store per block
  float* red = (float*)lds;
  __syncthreads();
  if (lane == 0) {
    red[wid * 4 + 0] = s_qr;
    red[wid * 4 + 1] = s_kr;
    red[wid * 4 + 2] = ss_qr;
    red[wid * 4 + 3] = ss_kr;
  }
  __syncthreads();
  if (t < 4) {
    float s = 0.f;
#pragma unroll
    for (int w2 = 0; w2 < 8; ++w2) s += red[w2 * 4 + t];
    p1part[((size_t)bg * 4 + it) * 4 + t] = s;
  }
}

// ---------------- K3c: qk BN stats via Grams: ss_qk = <Gq, Gk> ----------------
#define GQC 0
#define GKC 16896
#define GGQ 33792
#define GGK 38016

__global__ __launch_bounds__(256) void k_gram(const float* __restrict__ qkv,
                                              const float* __restrict__ qs,
                                              const float* __restrict__ qh,
                                              float* __restrict__ gpart) {
  __shared__ char gsh[42240];
  __shared__ float r1[4], r2[4];
  const int b = blockIdx.x >> 3, g = blockIdx.x & 7;
  const int t = threadIdx.x, lane = t & 63, wid = t >> 6;
  const int cg = lane & 15, hi = lane >> 4;

  // stage Qc[c][i], Kc[c][i] bf16, pitch 528B
  {
    int c = t >> 3, ch = (t & 7) * 32;
    int oq = g * 128 + c, ok = oq + 32;
    float sq = qs[oq], hq = qh[oq], sk = qs[ok], hk = qh[ok];
    const float* srq = qkv + ((size_t)b * OO + oq) * NN + ch;
    const float* srk = qkv + ((size_t)b * OO + ok) * NN + ch;
#pragma unroll
    for (int r = 0; r < 8; ++r) {
      float4 vq = *(const float4*)(srq + r * 4);
      float4 vk = *(const float4*)(srk + r * 4);
      short4 s4q = make_short4(f2bf_rne(vq.x * sq + hq), f2bf_rne(vq.y * sq + hq),
                               f2bf_rne(vq.z * sq + hq), f2bf_rne(vq.w * sq + hq));
      short4 s4k = make_short4(f2bf_rne(vk.x * sk + hk), f2bf_rne(vk.y * sk + hk),
                               f2bf_rne(vk.z * sk + hk), f2bf_rne(vk.w * sk + hk));
      *(short4*)(gsh + GQC + c * 528 + (ch + r * 4) * 2) = s4q;
      *(short4*)(gsh + GKC + c * 528 + (ch + r * 4) * 2) = s4k;
    }
  }
  __syncthreads();

  // Gram MFMA: waves 0-1 -> Gq row-tiles 0/1; waves 2-3 -> Gk
  {
    int base = (wid >> 1) ? GKC : GQC;
    int gbase = (wid >> 1) ? GGK : GGQ;
    int rt = wid & 1;
    f32x4 acc0 = (f32x4){0.f, 0.f, 0.f, 0.f};
    f32x4 acc1 = (f32x4){0.f, 0.f, 0.f, 0.f};
#pragma unroll
    for (int ks = 0; ks < 8; ++ks) {
      bf16x8 af = *(const bf16x8*)(gsh + base + (rt * 16 + cg) * 528 + ks * 64 + hi * 16);
      bf16x8 b0 = *(const bf16x8*)(gsh + base + (cg) * 528 + ks * 64 + hi * 16);
      bf16x8 b1 = *(const bf16x8*)(gsh + base + (16 + cg) * 528 + ks * 64 + hi * 16);
      acc0 = __builtin_amdgcn_mfma_f32_16x16x32_bf16(af, b0, acc0, 0, 0, 0);
      acc1 = __builtin_amdgcn_mfma_f32_16x16x32_bf16(af, b1, acc1, 0, 0, 0);
    }
#pragma unroll
    for (int e = 0; e < 4; ++e) {
      int row = rt * 16 + hi * 4 + e;
      *(float*)(gsh + gbase + (row * 33 + cg) * 4) = acc0[e];
      *(float*)(gsh + gbase + (row * 33 + 16 + cg) * 4) = acc1[e];
    }
  }
  __syncthreads();

  float ssqk = 0.f;
#pragma unroll
  for (int pp = 0; pp < 4; ++pp) {
    int p = t * 4 + pp;
    int c = p >> 5, cp = p & 31;
    float gq = *(const float*)(gsh + GGQ + (c * 33 + cp) * 4);
    float gk = *(const float*)(gsh + GGK + (c * 33 + cp) * 4);
    ssqk += gq * gk;
  }
  // column sums for means
  float sq = 0.f, sk = 0.f;
  {
    int c = t >> 3, ch = (t & 7) * 32;
#pragma unroll 8
    for (int r = 0; r < 32; ++r) {
      sq += bf2f(*(const unsigned short*)(gsh + GQC + c * 528 + (ch + r) * 2));
      sk += bf2f(*(const unsigned short*)(gsh + GKC + c * 528 + (ch + r) * 2));
    }
  }
#pragma unroll
  for (int m = 1; m < 8; m <<= 1) { sq += __shfl_xor(sq, m); sk += __shfl_xor(sk, m); }
  float sprod = ((t & 7) == 0) ? sq * sk : 0.f;
#pragma unroll
  for (int m = 1; m < 64; m <<= 1) { ssqk += __shfl_xor(ssqk, m); sprod += __shfl_xor(sprod, m); }
  if (lane == 0) { r1[wid] = ssqk; r2[wid] = sprod; }
  __syncthreads();
  if (t == 0) {
    gpart[blockIdx.x * 2 + 0] = r1[0] + r1[1] + r1[2] + r1[3];
    gpart[blockIdx.x * 2 + 1] = r2[0] + r2[1] + r2[2] + r2[3];
  }
}

// ---------------- finalize: reduce partials + sim BN coefficients ----------------
__global__ void k_sim_finalize(const float* __restrict__ p1part,
                               const float* __restrict__ gpart,
                               const float* __restrict__ gs,
                               const float* __restrict__ bs,
                               float* __restrict__ simscale,
                               float* __restrict__ simshift) {
  __shared__ float sm[48];
  __shared__ float sh[24];
  const int t = threadIdx.x;
  if (t < 32) {
    int g = t & 7, stat = t >> 3;        // 0:s_qr 1:s_kr 2:ss_qr 3:ss_kr
    float s = 0.f;
    for (int i = 0; i < 256; ++i)        // 64 b x 4 it
      s += p1part[(((size_t)(i >> 2) * 8 + g) * 4 + (i & 3)) * 4 + stat];
    const float fs[4] = {F_QR, F_KR, F_QR * F_QR, F_KR * F_KR};
    const int dst[4] = {8, 16, 32, 40};
    sm[dst[stat] + g] = s * fs[stat];
  } else if (t < 48) {
    int g = t & 7, which = (t >> 3) & 1; // 0:ssqk 1:sprod(mean)
    float s = 0.f;
    for (int b = 0; b < 64; ++b) s += gpart[(b * 8 + g) * 2 + which];
    if (which) sm[g] = s; else sm[24 + g] = s;
  }
  __syncthreads();
  if (t < 24) {
    const float inv = 1.f / (64.f * 256.f * 256.f);
    float m = sm[t] * inv;
    float var = sm[24 + t] * inv - m * m;
    float a = gs[t] * rsqrtf(var + 1e-5f);
    simscale[t] = a;
    sh[t] = bs[t] - m * a;
  }
  __syncthreads();
  if (t < 8) simshift[t] = sh[t] + sh[8 + t] + sh[16 + t];
}

// ---------------- pass2: all-MFMA, 8 waves, pitched LDS (unchanged r7) -------
#define MG_OFF   0
#define SMX_OFF  0
#define SMS_OFF  512
#define KH_OFF   45056
#define KL_OFF   65536
#define RST_OFF  86016
#define QH_OFF   111616
#define QL_OFF   116736
#define VB_OFF   45056
#define PF_OFF   86016
#define RV_OFF   121856
#define P2_LDS   163840
#define MQP 656
#define GP  176
#define PFP 528
#define RVP 656

__global__ __launch_bounds__(512) void k_pass2(const float* __restrict__ qkv,
                                               const float* __restrict__ relp,
                                               const float* __restrict__ qs,
                                               const float* __restrict__ qh,
                                               const float* __restrict__ simscale,
                                               float* __restrict__ svbuf,
                                               float* __restrict__ svebuf) {
  extern __shared__ char lds[];
  const int it = blockIdx.x, bg = blockIdx.y;
  const int b = bg >> 3, g = bg & 7, i0 = it * 64;
  const int t = threadIdx.x, lane = t & 63, wid = t >> 6;
  const int cg = lane & 15, hi = lane >> 4;
  const int wi = wid & 3, wj = wid >> 2;
  const float aQK = simscale[g];
  const float aQR = F_QR * simscale[8 + g];
  const float aKR = F_KR * simscale[16 + g];

  {
    int c = t >> 4;
    int o = g * 128 + c;
    float sc = qs[o], hh = qh[o];
    int i4 = (t & 15) * 4;
    float4 v = *(const float4*)(qkv + ((size_t)b * OO + o) * NN + i0 + i4);
    float vv[4] = {v.x * sc + hh, v.y * sc + hh, v.z * sc + hh, v.w * sc + hh};
#pragma unroll
    for (int e = 0; e < 4; ++e) {
      int iL = i4 + e;
      unsigned short hb = (unsigned short)(__float_as_uint(vv[e]) >> 16);
      *(unsigned short*)(lds + QH_OFF + iL * QP + c * 2) = hb;
      *(unsigned short*)(lds + QL_OFF + iL * QP + c * 2) = f2bf_rne(vv[e] - bf2f(hb));
    }
  }
  {
    int c = t >> 4;
    int o = g * 128 + 32 + c;
    float sc = qs[o], hh = qh[o];
    const float* src = qkv + ((size_t)b * OO + o) * NN;
#pragma unroll
    for (int r = 0; r < 4; ++r) {
      int j4 = ((t & 15) + 16 * r) * 4;
      float4 v = *(const float4*)(src + j4);
      float vv[4] = {v.x * sc + hh, v.y * sc + hh, v.z * sc + hh, v.w * sc + hh};
#pragma unroll
      for (int e = 0; e < 4; ++e) {
        int j = j4 + e;
        unsigned short hb = (unsigned short)(__float_as_uint(vv[e]) >> 16);
        *(unsigned short*)(lds + KH_OFF + j * QP + c * 2) = hb;
        *(unsigned short*)(lds + KL_OFF + j * QP + c * 2) = f2bf_rne(vv[e] - bf2f(hb));
      }
    }
  }
  {
    int c = t >> 4;
    const float* src = relp + c * 512 + i0;
#pragma unroll
    for (int r = 0; r < 5; ++r) {
      int u4 = ((t & 15) + 16 * r) * 4;
      float4 v = *(const float4*)(src + u4);
      float vv[4] = {v.x, v.y, v.z, v.w};
#pragma unroll
      for (int e = 0; e < 4; ++e)
        *(unsigned short*)(lds + RST_OFF + (u4 + e) * QP + c * 2) = f2bf_rne(vv[e]);
    }
  }
  __syncthreads();

  f32x4 p[8];
#pragma unroll
  for (int n = 0; n < 8; ++n) p[n] = (f32x4){0.f, 0.f, 0.f, 0.f};

  int qrow = wi * 16 + cg;
  bf16x8 qhf = *(const bf16x8*)(lds + QH_OFF + qrow * QP + hi * 16);
  bf16x8 qlf = *(const bf16x8*)(lds + QL_OFF + qrow * QP + hi * 16);
#pragma unroll
  for (int n = 0; n < 8; ++n) {
    int krow = (wj * 8 + n) * 16 + cg;
    bf16x8 khf = *(const bf16x8*)(lds + KH_OFF + krow * QP + hi * 16);
    bf16x8 klf = *(const bf16x8*)(lds + KL_OFF + krow * QP + hi * 16);
    p[n] = __builtin_amdgcn_mfma_f32_16x16x32_bf16(qhf, khf, p[n], 0, 0, 0);
    p[n] = __builtin_amdgcn_mfma_f32_16x16x32_bf16(qhf, klf, p[n], 0, 0, 0);
    p[n] = __builtin_amdgcn_mfma_f32_16x16x32_bf16(qlf, khf, p[n], 0, 0, 0);
  }
#pragma unroll
  for (int n = 0; n < 8; ++n)
#pragma unroll
    for (int e = 0; e < 4; ++e) p[n][e] *= aQK;

#pragma unroll
  for (int m5 = 0; m5 < 10; ++m5) {
    int ntq = wj * 10 + m5;
    bf16x8 rf = *(const bf16x8*)(lds + RST_OFF + (ntq * 16 + cg) * QP + hi * 16);
    f32x4 m = (f32x4){0.f, 0.f, 0.f, 0.f};
    m = __builtin_amdgcn_mfma_f32_16x16x32_bf16(qhf, rf, m, 0, 0, 0);
#pragma unroll
    for (int e = 0; e < 4; ++e) {
      int iL = wi * 16 + hi * 4 + e;
      *(unsigned short*)(lds + MG_OFF + iL * MQP + (ntq * 16 + cg) * 2) = f2bf_rne(m[e]);
    }
  }
  __syncthreads();

#pragma unroll
  for (int n = 0; n < 8; ++n)
#pragma unroll
    for (int e = 0; e < 4; ++e) {
      int iL = wi * 16 + hi * 4 + e;
      int ul = iL - ((wj * 8 + n) * 16 + cg) + 255;
      p[n][e] += aQR * bf2f(*(const unsigned short*)(lds + MG_OFF + iL * MQP + ul * 2));
    }
  {
    int c = t >> 4;
    const float* src = relp + (32 + c) * 512 + (192 - i0);
#pragma unroll
    for (int r = 0; r < 5; ++r) {
      int u4 = ((t & 15) + 16 * r) * 4;
      float4 v = *(const float4*)(src + u4);
      float vv[4] = {v.x, v.y, v.z, v.w};
#pragma unroll
      for (int e = 0; e < 4; ++e)
        *(unsigned short*)(lds + RST_OFF + (u4 + e) * QP + c * 2) = f2bf_rne(vv[e]);
    }
  }
  __syncthreads();

#pragma unroll
  for (int jj = 0; jj < 2; ++jj) {
    int jt = wid * 2 + jj;
    bf16x8 kf = *(const bf16x8*)(lds + KH_OFF + (jt * 16 + cg) * QP + hi * 16);
#pragma unroll
    for (int n5 = 0; n5 < 5; ++n5) {
      bf16x8 rf = *(const bf16x8*)(lds + RST_OFF + ((jt + n5) * 16 + cg) * QP + hi * 16);
      f32x4 gacc = (f32x4){0.f, 0.f, 0.f, 0.f};
      gacc = __builtin_amdgcn_mfma_f32_16x16x32_bf16(kf, rf, gacc, 0, 0, 0);
#pragma unroll
      for (int e = 0; e < 4; ++e) {
        int j = jt * 16 + hi * 4 + e;
        *(unsigned short*)(lds + MG_OFF + j * GP + (n5 * 16 + cg) * 2) = f2bf_rne(gacc[e]);
      }
    }
  }
  __syncthreads();

#pragma unroll
  for (int n = 0; n < 8; ++n)
#pragma unroll
    for (int e = 0; e < 4; ++e) {
      int iL = wi * 16 + hi * 4 + e;
      int j = (wj * 8 + n) * 16 + cg;
      int sl = cg + 63 - iL;
      p[n][e] += aKR * bf2f(*(const unsigned short*)(lds + MG_OFF + j * GP + sl * 2));
    }
  __syncthreads();

  {
    float mloc[4];
#pragma unroll
    for (int e = 0; e < 4; ++e) {
      float m = p[0][e];
#pragma unroll
      for (int n = 1; n < 8; ++n) m = fmaxf(m, p[n][e]);
#pragma unroll
      for (int k = 1; k < 16; k <<= 1) m = fmaxf(m, __shfl_xor(m, k));
      mloc[e] = m;
    }
    if (cg == 0) {
#pragma unroll
      for (int e = 0; e < 4; ++e)
        *(float*)(lds + SMX_OFF + (wj * 64 + wi * 16 + hi * 4 + e) * 4) = mloc[e];
    }
    __syncthreads();
    float sloc[4];
#pragma unroll
    for (int e = 0; e < 4; ++e) {
      int iL = wi * 16 + hi * 4 + e;
      float m = fmaxf(*(const float*)(lds + SMX_OFF + iL * 4),
                      *(const float*)(lds + SMX_OFF + (64 + iL) * 4));
      float s = 0.f;
#pragma unroll
      for (int n = 0; n < 8; ++n) { float ev = __expf(p[n][e] - m); p[n][e] = ev; s += ev; }
#pragma unroll
      for (int k = 1; k < 16; k <<= 1) s += __shfl_xor(s, k);
      sloc[e] = s;
    }
    if (cg == 0) {
#pragma unroll
      for (int e = 0; e < 4; ++e)
        *(float*)(lds + SMS_OFF + (wj * 64 + wi * 16 + hi * 4 + e) * 4) = sloc[e];
    }
    __syncthreads();
#pragma unroll
    for (int e = 0; e < 4; ++e) {
      int iL = wi * 16 + hi * 4 + e;
      float s = *(const float*)(lds + SMS_OFF + iL * 4) +
                *(const float*)(lds + SMS_OFF + (64 + iL) * 4);
      float inv = 1.f / s;
#pragma unroll
      for (int n = 0; n < 8; ++n) p[n][e] *= inv;
    }
  }
  __syncthreads();

#pragma unroll
  for (int r = 0; r < 6; ++r) {
    int idx = r * 512 + t;
    if (idx < 2816) *(float4*)(lds + idx * 16) = make_float4(0.f, 0.f, 0.f, 0.f);
  }
  __syncthreads();

#pragma unroll
  for (int n = 0; n < 8; ++n)
#pragma unroll
    for (int e = 0; e < 4; ++e) {
      int iL = wi * 16 + hi * 4 + e;
      int j = (wj * 8 + n) * 16 + cg;
      unsigned short hv = f2bf_rne(p[n][e]);
      *(unsigned short*)(lds + PF_OFF + iL * PFP + j * 2) = hv;
      int us = iL + 255 - j;
      *(unsigned short*)(lds + MG_OFF + iL * MQP + us * 2) = hv;
    }
  {
    int cp = (t >> 2) & 63, half = t >> 8;
    int o = g * 128 + 64 + cp;
    float sc = qs[o], hh = qh[o];
    const float* src = qkv + ((size_t)b * OO + o) * NN;
#pragma unroll
    for (int r = 0; r < 8; ++r) {
      int ch = (t & 3) + half * 4 + 8 * r;
      float4 v = *(const float4*)(src + ch * 4);
      short4 s4 = make_short4(f2bf_rne(v.x * sc + hh), f2bf_rne(v.y * sc + hh),
                              f2bf_rne(v.z * sc + hh), f2bf_rne(v.w * sc + hh));
      *(short4*)(lds + VB_OFF + cp * PFP + ch * 8) = s4;
    }
    const float* srv = relp + (size_t)(64 + cp) * 512 + i0;
#pragma unroll
    for (int r = 0; r < 10; ++r) {
      int ch = (t & 3) + half * 4 + 8 * r;
      float4 v = *(const float4*)(srv + ch * 4);
      short4 s4 = make_short4(f2bf_rne(v.x), f2bf_rne(v.y), f2bf_rne(v.z), f2bf_rne(v.w));
      *(short4*)(lds + RV_OFF + cp * RVP + ch * 8) = s4;
    }
  }
  __syncthreads();

  {
    int prow = wi * 16 + cg;
    bf16x8 af[8];
#pragma unroll
    for (int ks = 0; ks < 8; ++ks)
      af[ks] = *(const bf16x8*)(lds + PF_OFF + prow * PFP + ks * 64 + hi * 16);
#pragma unroll
    for (int n = 0; n < 2; ++n) {
      int ntv = wj * 2 + n;
      f32x4 acc = (f32x4){0.f, 0.f, 0.f, 0.f};
#pragma unroll
      for (int ks = 0; ks < 8; ++ks) {
        bf16x8 bfv = *(const bf16x8*)(lds + VB_OFF + (ntv * 16 + cg) * PFP + ks * 64 + hi * 16);
        acc = __builtin_amdgcn_mfma_f32_16x16x32_bf16(af[ks], bfv, acc, 0, 0, 0);
      }
      float* dst = svbuf + ((size_t)(b * 512 + g * 64 + ntv * 16 + cg)) * NN + i0 + wi * 16 + hi * 4;
      *(float4*)dst = make_float4(acc[0], acc[1], acc[2], acc[3]);
    }
    bf16x8 ae[10];
#pragma unroll
    for (int ks = 0; ks < 10; ++ks)
      ae[ks] = *(const bf16x8*)(lds + MG_OFF + prow * MQP + ks * 64 + hi * 16);
#pragma unroll
    for (int n = 0; n < 2; ++n) {
      int ntv = wj * 2 + n;
      f32x4 acc = (f32x4){0.f, 0.f, 0.f, 0.f};
#pragma unroll
      for (int ks = 0; ks < 10; ++ks) {
        bf16x8 bfr = *(const bf16x8*)(lds + RV_OFF + (ntv * 16 + cg) * RVP + ks * 64 + hi * 16);
        acc = __builtin_amdgcn_mfma_f32_16x16x32_bf16(ae[ks], bfr, acc, 0, 0, 0);
      }
      float* dst = svebuf + ((size_t)(b * 512 + g * 64 + ntv * 16 + cg)) * NN + i0 + wi * 16 + hi * 4;
      *(float4*)dst = make_float4(acc[0] * F_SVE, acc[1] * F_SVE, acc[2] * F_SVE, acc[3] * F_SVE);
    }
  }
}

// ---------------- K6: final BN stats over sv / sve ----------------
__global__ __launch_bounds__(256) void k_out_stats(const float* __restrict__ svbuf,
                                                   const float* __restrict__ svebuf,
                                                   const float* __restrict__ go,
                                                   const float* __restrict__ bo,
                                                   float* __restrict__ osc,
                                                   float* __restrict__ osh) {
  const int bid = blockIdx.x;
  const int arr = bid >> 9, pch = bid & 511;
  const float* buf = arr ? svebuf : svbuf;
  const int t = threadIdx.x;
  float s = 0.f, ss = 0.f;
  for (int b = 0; b < BB; ++b) {
    float v = buf[((size_t)b * 512 + pch) * NN + t];
    s += v; ss += v * v;
  }
#pragma unroll
  for (int m = 1; m < 64; m <<= 1) { s += __shfl_xor(s, m); ss += __shfl_xor(ss, m); }
  __shared__ float rs[4], rss[4];
  int wv = t >> 6;
  if ((t & 63) == 0) { rs[wv] = s; rss[wv] = ss; }
  __syncthreads();
  if (t == 0) {
    s = rs[0] + rs[1] + rs[2] + rs[3];
    ss = rss[0] + rss[1] + rss[2] + rss[3];
    const float inv = 1.f / 16384.f;
    float m = s * inv;
    float var = ss * inv - m * m;
    float r = rsqrtf(var + 1e-5f);
    int o = pch * 2 + arr;
    float sc = go[o] * r;
    osc[bid] = sc;
    osh[bid] = bo[o] - m * sc;
  }
}

// ---------------- K7: combine ----------------
__global__ __launch_bounds__(256) void k_final(const float* __restrict__ svbuf,
                                               const float* __restrict__ svebuf,
                                               const float* __restrict__ osc,
                                               const float* __restrict__ osh,
                                               float* __restrict__ out) {
  const size_t f = (size_t)blockIdx.x * 256 + threadIdx.x;
  const int pch = (int)((f >> 6) & 511);
  float4 a = ((const float4*)svbuf)[f];
  float4 e = ((const float4*)svebuf)[f];
  float s1 = osc[pch], h1 = osh[pch];
  float s2 = osc[512 + pch], h2 = osh[512 + pch];
  float hh = h1 + h2;
  float4 o;
  o.x = a.x * s1 + e.x * s2 + hh;
  o.y = a.y * s1 + e.y * s2 + hh;
  o.z = a.z * s1 + e.z * s2 + hh;
  o.w = a.w * s1 + e.w * s2 + hh;
  ((float4*)out)[f] = o;
}

extern "C" void kernel_launch(void* const* d_in, const int* in_sizes, int n_in,
                              void* d_out, int out_size, void* d_ws, size_t ws_size,
                              hipStream_t stream) {
  const float* x     = (const float*)d_in[0];
  const float* w     = (const float*)d_in[1];
  const float* rel   = (const float*)d_in[2];
  const float* g_qkv = (const float*)d_in[3];
  const float* b_qkv = (const float*)d_in[4];
  const float* g_sim = (const float*)d_in[5];
  const float* b_sim = (const float*)d_in[6];
  const float* g_out = (const float*)d_in[7];
  const float* b_out = (const float*)d_in[8];

  float* ws = (float*)d_ws;
  float* qkv      = ws;
  float* sv       = qkv + 16777216;
  float* sve      = sv + 8388608;
  float* qs       = sve + 8388608;
  float* qh       = qs + 1024;
  float* simscale = qh + 1024;        // 24
  float* simshift = simscale + 24;    // 8
  float* osc      = simshift + 8;     // 1024
  float* osh      = osc + 1024;       // 1024
  float* p1part   = osh + 1024;       // 8192 (2048 blocks x 4 stats)
  float* gpart    = p1part + 8192;    // 1024 (512 blocks x 2)

  float* relp = (float*)d_out;

  hipFuncSetAttribute((const void*)k_pass2, hipFuncAttributeMaxDynamicSharedMemorySize, P2_LDS);
  hipFuncSetAttribute((const void*)k_p1lite, hipFuncAttributeMaxDynamicSharedMemorySize, P1_LDS);

  k_relpad<<<128, 256, 0, stream>>>(rel, relp);
  k_qkv_gemm<<<dim3(2, 8, 64), 256, 0, stream>>>(x, w, qkv);
  k_qkv_stats<<<1024, 256, 0, stream>>>(qkv, g_qkv, b_qkv, qs, qh);
  k_p1lite<<<dim3(4, 512), 512, P1_LDS, stream>>>(qkv, relp, qs, qh, p1part);
  k_gram<<<512, 256, 0, stream>>>(qkv, qs, qh, gpart);
  k_sim_finalize<<<1, 64, 0, stream>>>(p1part, gpart, g_sim, b_sim, simscale, simshift);
  k_pass2<<<dim3(4, 512), 512, P2_LDS, stream>>>(qkv, relp, qs, qh, simscale, sv, sve);
  k_out_stats<<<1024, 256, 0, stream>>>(sv, sve, g_out, b_out, osc, osh);
  k_final<<<8192, 256, 0, stream>>>(sv, sve, osc, osh, (float*)d_out);
}

// Round 11
// 411.097 us; speedup vs baseline: 2.0653x; 1.0070x over previous
//
#include <hip/hip_runtime.h>

#define NN 256
#define CC 512
#define OO 1024
#define BB 64

#define F_QR 0.1f
#define F_KR 0.1f
#define F_SVE 0.1f

typedef __attribute__((ext_vector_type(8))) short bf16x8;
typedef __attribute__((ext_vector_type(4))) float f32x4;

__device__ inline unsigned short f2bf_rne(float f) {
  unsigned u = __float_as_uint(f);
  u += 0x7fffu + ((u >> 16) & 1u);
  return (unsigned short)(u >> 16);
}

__device__ inline float bf2f(unsigned short h) {
  return __uint_as_float((unsigned)h << 16);
}

// ---------------- K0: pad rel rows 511 -> 512 ----------------
__global__ void k_relpad(const float* __restrict__ rel, float* __restrict__ relp) {
  const int row = blockIdx.x;
  const int t = threadIdx.x;
  for (int u = t; u < 511; u += 256) relp[row * 512 + u] = rel[row * 511 + u];
  if (t == 0) relp[row * 512 + 511] = 0.f;
}

// ---------------- K0b: fp32 -> split bf16 hi/lo (hoisted out of gemm) ---------
// Same truncate-hi / RNE-lo math as the old in-gemm conversion -> gemm output
// is bit-identical; gemm inner loop loses ALL conversion VALU work.
__global__ __launch_bounds__(256) void k_split(const float* __restrict__ src,
                                               unsigned short* __restrict__ dh,
                                               unsigned short* __restrict__ dl,
                                               int n4) {
  int i = blockIdx.x * 256 + threadIdx.x;
  const int stride = gridDim.x * 256;
  for (; i < n4; i += stride) {
    float4 v = ((const float4*)src)[i];
    float a[4] = {v.x, v.y, v.z, v.w};
    unsigned short h4[4], l4[4];
#pragma unroll
    for (int e = 0; e < 4; ++e) {
      unsigned short hb = (unsigned short)(__float_as_uint(a[e]) >> 16);
      h4[e] = hb;
      l4[e] = f2bf_rne(a[e] - bf2f(hb));
    }
    *(short4*)&dh[i * 4] = make_short4(h4[0], h4[1], h4[2], h4[3]);
    *(short4*)&dl[i * 4] = make_short4(l4[0], l4[1], l4[2], l4[3]);
  }
}

// ---------------- K1: qkv GEMM (split-bf16 MFMA; inputs pre-split) ------------
__global__ __launch_bounds__(256) void k_qkv_gemm(const unsigned short* __restrict__ xh,
                                                  const unsigned short* __restrict__ xl,
                                                  const unsigned short* __restrict__ wh,
                                                  const unsigned short* __restrict__ wl,
                                                  float* __restrict__ qkv) {
  __shared__ unsigned short Ah[128][40];
  __shared__ unsigned short Al[128][40];
  __shared__ unsigned short Bh[128][40];
  __shared__ unsigned short Bl[128][40];

  const int b = blockIdx.z, o0 = blockIdx.y * 128, n0 = blockIdx.x * 128;
  const int t = threadIdx.x;
  const int lane = t & 63, wid = t >> 6;
  const int wr = wid >> 1, wc = wid & 1;
  const int frow = lane & 15;
  const int koff = (lane >> 4) * 8;

  f32x4 acc[4][4];
#pragma unroll
  for (int i = 0; i < 4; ++i)
#pragma unroll
    for (int j = 0; j < 4; ++j) acc[i][j] = (f32x4){0.f, 0.f, 0.f, 0.f};

  for (int c0 = 0; c0 < CC; c0 += 32) {
    if (c0) __syncthreads();
#pragma unroll
    for (int r = 0; r < 2; ++r) {
      int f = t + 256 * r;              // 0..511 = 128 rows x 4 chunks
      int row = f >> 2, q = (f & 3) * 8;
      size_t aoff = (size_t)(o0 + row) * CC + c0 + q;
      size_t boff = ((size_t)b * NN + n0 + row) * CC + c0 + q;
      *(bf16x8*)&Ah[row][q] = *(const bf16x8*)&wh[aoff];
      *(bf16x8*)&Al[row][q] = *(const bf16x8*)&wl[aoff];
      *(bf16x8*)&Bh[row][q] = *(const bf16x8*)&xh[boff];
      *(bf16x8*)&Bl[row][q] = *(const bf16x8*)&xl[boff];
    }
    __syncthreads();

    bf16x8 fah[4], fal[4], fbh[4], fbl[4];
#pragma unroll
    for (int mi = 0; mi < 4; ++mi) {
      int rr = wr * 64 + mi * 16 + frow;
      fah[mi] = *(const bf16x8*)&Ah[rr][koff];
      fal[mi] = *(const bf16x8*)&Al[rr][koff];
    }
#pragma unroll
    for (int nj = 0; nj < 4; ++nj) {
      int rr = wc * 64 + nj * 16 + frow;
      fbh[nj] = *(const bf16x8*)&Bh[rr][koff];
      fbl[nj] = *(const bf16x8*)&Bl[rr][koff];
    }
#pragma unroll
    for (int mi = 0; mi < 4; ++mi)
#pragma unroll
      for (int nj = 0; nj < 4; ++nj) {
        acc[mi][nj] = __builtin_amdgcn_mfma_f32_16x16x32_bf16(fah[mi], fbh[nj], acc[mi][nj], 0, 0, 0);
        acc[mi][nj] = __builtin_amdgcn_mfma_f32_16x16x32_bf16(fah[mi], fbl[nj], acc[mi][nj], 0, 0, 0);
        acc[mi][nj] = __builtin_amdgcn_mfma_f32_16x16x32_bf16(fal[mi], fbh[nj], acc[mi][nj], 0, 0, 0);
      }
  }

#pragma unroll
  for (int mi = 0; mi < 4; ++mi) {
    int orow = o0 + wr * 64 + mi * 16 + (lane >> 4) * 4;
#pragma unroll
    for (int nj = 0; nj < 4; ++nj) {
      int ncol = n0 + wc * 64 + nj * 16 + frow;
      float* dst = qkv + ((size_t)b * OO + orow) * NN + ncol;
#pragma unroll
      for (int j = 0; j < 4; ++j) dst[(size_t)j * NN] = acc[mi][nj][j];
    }
  }
}

// ---------------- K2: per-channel BN scale/shift for qkv ----------------
__global__ __launch_bounds__(256) void k_qkv_stats(const float* __restrict__ qkv,
                                                   const float* __restrict__ gq,
                                                   const float* __restrict__ bq,
                                                   float* __restrict__ qs,
                                                   float* __restrict__ qh) {
  const int o = blockIdx.x;
  const int t = threadIdx.x;
  float s = 0.f, ss = 0.f;
  for (int b = 0; b < BB; ++b) {
    float v = qkv[((size_t)b * OO + o) * NN + t];
    s += v; ss += v * v;
  }
#pragma unroll
  for (int m = 1; m < 64; m <<= 1) { s += __shfl_xor(s, m); ss += __shfl_xor(ss, m); }
  __shared__ float rs[4], rss[4];
  int wv = t >> 6;
  if ((t & 63) == 0) { rs[wv] = s; rss[wv] = ss; }
  __syncthreads();
  if (t == 0) {
    s = rs[0] + rs[1] + rs[2] + rs[3];
    ss = rss[0] + rss[1] + rss[2] + rss[3];
    const float inv = 1.f / (float)(BB * NN);
    float m = s * inv;
    float var = ss * inv - m * m;
    float r = rsqrtf(var + 1e-5f);
    float sc = gq[o] * r;
    qs[o] = sc;
    qh[o] = bq[o] - m * sc;
  }
}

// ---------------- K3: pass1-lite — qr/kr BN stats via MFMA band-sums ----------
#define P1_QH 0
#define P1_QL 5120
#define P1_KH 10240
#define P1_KL 15360
#define P1_RQ 20480
#define P1_RK 46080
#define P1_LDS 71680
#define QP 80

__global__ __launch_bounds__(512) void k_p1lite(const float* __restrict__ qkv,
                                                const float* __restrict__ relp,
                                                const float* __restrict__ qs,
                                                const float* __restrict__ qh,
                                                float* __restrict__ p1part) {
  extern __shared__ char lds[];
  const int it = blockIdx.x, bg = blockIdx.y;
  const int b = bg >> 3, g = bg & 7, i0 = it * 64;
  const int t = threadIdx.x, lane = t & 63, wid = t >> 6;
  const int cg = lane & 15, hi = lane >> 4;
  const int wi = wid & 3, wj = wid >> 2;

  {
    int c = t >> 4;
    int o = g * 128 + c;
    float sc = qs[o], hh = qh[o];
    int i4 = (t & 15) * 4;
    float4 v = *(const float4*)(qkv + ((size_t)b * OO + o) * NN + i0 + i4);
    float vv[4] = {v.x * sc + hh, v.y * sc + hh, v.z * sc + hh, v.w * sc + hh};
#pragma unroll
    for (int e = 0; e < 4; ++e) {
      unsigned short hb = (unsigned short)(__float_as_uint(vv[e]) >> 16);
      *(unsigned short*)(lds + P1_QH + (i4 + e) * QP + c * 2) = hb;
      *(unsigned short*)(lds + P1_QL + (i4 + e) * QP + c * 2) = f2bf_rne(vv[e] - bf2f(hb));
    }
  }
  {
    int c = t >> 4;
    int o = g * 128 + 32 + c;
    float sc = qs[o], hh = qh[o];
    int i4 = (t & 15) * 4;
    float4 v = *(const float4*)(qkv + ((size_t)b * OO + o) * NN + i0 + i4);
    float vv[4] = {v.x * sc + hh, v.y * sc + hh, v.z * sc + hh, v.w * sc + hh};
#pragma unroll
    for (int e = 0; e < 4; ++e) {
      unsigned short hb = (unsigned short)(__float_as_uint(vv[e]) >> 16);
      *(unsigned short*)(lds + P1_KH + (i4 + e) * QP + c * 2) = hb;
      *(unsigned short*)(lds + P1_KL + (i4 + e) * QP + c * 2) = f2bf_rne(vv[e] - bf2f(hb));
    }
  }
  {
    int c = t >> 4;
    const float* sq = relp + c * 512 + i0;
    const float* sk = relp + (32 + c) * 512 + i0;
#pragma unroll
    for (int r = 0; r < 5; ++r) {
      int u4 = ((t & 15) + 16 * r) * 4;
      float4 vq = *(const float4*)(sq + u4);
      float4 vk = *(const float4*)(sk + u4);
      float aq[4] = {vq.x, vq.y, vq.z, vq.w};
      float ak[4] = {vk.x, vk.y, vk.z, vk.w};
#pragma unroll
      for (int e = 0; e < 4; ++e) {
        *(unsigned short*)(lds + P1_RQ + (u4 + e) * QP + c * 2) = f2bf_rne(aq[e]);
        *(unsigned short*)(lds + P1_RK + (u4 + e) * QP + c * 2) = f2bf_rne(ak[e]);
      }
    }
  }
  __syncthreads();

  float s_qr = 0.f, ss_qr = 0.f, s_kr = 0.f, ss_kr = 0.f;
  const int arow = wi * 16 + cg;
  bf16x8 qhf = *(const bf16x8*)(lds + P1_QH + arow * QP + hi * 16);
  bf16x8 qlf = *(const bf16x8*)(lds + P1_QL + arow * QP + hi * 16);
  bf16x8 khf = *(const bf16x8*)(lds + P1_KH + arow * QP + hi * 16);
  bf16x8 klf = *(const bf16x8*)(lds + P1_KL + arow * QP + hi * 16);

#pragma unroll
  for (int m5 = 0; m5 < 10; ++m5) {
    int ntq = wj * 10 + m5;
    int brow = ntq * 16 + cg;
    bf16x8 rqf = *(const bf16x8*)(lds + P1_RQ + brow * QP + hi * 16);
    f32x4 mq = (f32x4){0.f, 0.f, 0.f, 0.f};
    mq = __builtin_amdgcn_mfma_f32_16x16x32_bf16(qhf, rqf, mq, 0, 0, 0);
    mq = __builtin_amdgcn_mfma_f32_16x16x32_bf16(qlf, rqf, mq, 0, 0, 0);
    bf16x8 rkf = *(const bf16x8*)(lds + P1_RK + brow * QP + hi * 16);
    f32x4 mk = (f32x4){0.f, 0.f, 0.f, 0.f};
    mk = __builtin_amdgcn_mfma_f32_16x16x32_bf16(khf, rkf, mk, 0, 0, 0);
    mk = __builtin_amdgcn_mfma_f32_16x16x32_bf16(klf, rkf, mk, 0, 0, 0);
#pragma unroll
    for (int e = 0; e < 4; ++e) {
      int rowL = wi * 16 + hi * 4 + e;
      int u = ntq * 16 + cg;
      if ((unsigned)(u - rowL) < 256u) {
        s_qr += mq[e]; ss_qr += mq[e] * mq[e];
        s_kr += mk[e]; ss_kr += mk[e] * mk[e];
      }
    }
  }

#pragma unroll
  for (int m = 1; m < 64; m <<= 1) {
    s_qr += __shfl_xor(s_qr, m);
    ss_qr += __shfl_xor(ss_qr, m);
    s_kr += __shfl_xor(s_kr, m);
    ss_kr += __shfl_xor(ss_kr, m);
  }
  float* red = (float*)lds;
  __syncthreads();
  if (lane == 0) {
    red[wid * 4 + 0] = s_qr;
    red[wid * 4 + 1] = s_kr;
    red[wid * 4 + 2] = ss_qr;
    red[wid * 4 + 3] = ss_kr;
  }
  __syncthreads();
  if (t < 4) {
    float s = 0.f;
#pragma unroll
    for (int w2 = 0; w2 < 8; ++w2) s += red[w2 * 4 + t];
    p1part[((size_t)bg * 4 + it) * 4 + t] = s;
  }
}

// ---------------- K3c: qk BN stats via Grams: ss_qk = <Gq, Gk> ----------------
#define GQC 0
#define GKC 16896
#define GGQ 33792
#define GGK 38016

__global__ __launch_bounds__(256) void k_gram(const float* __restrict__ qkv,
                                              const float* __restrict__ qs,
                                              const float* __restrict__ qh,
                                              float* __restrict__ gpart) {
  __shared__ char gsh[42240];
  __shared__ float r1[4], r2[4];
  const int b = blockIdx.x >> 3, g = blockIdx.x & 7;
  const int t = threadIdx.x, lane = t & 63, wid = t >> 6;
  const int cg = lane & 15, hi = lane >> 4;

  {
    int c = t >> 3, ch = (t & 7) * 32;
    int oq = g * 128 + c, ok = oq + 32;
    float sq = qs[oq], hq = qh[oq], sk = qs[ok], hk = qh[ok];
    const float* srq = qkv + ((size_t)b * OO + oq) * NN + ch;
    const float* srk = qkv + ((size_t)b * OO + ok) * NN + ch;
#pragma unroll
    for (int r = 0; r < 8; ++r) {
      float4 vq = *(const float4*)(srq + r * 4);
      float4 vk = *(const float4*)(srk + r * 4);
      short4 s4q = make_short4(f2bf_rne(vq.x * sq + hq), f2bf_rne(vq.y * sq + hq),
                               f2bf_rne(vq.z * sq + hq), f2bf_rne(vq.w * sq + hq));
      short4 s4k = make_short4(f2bf_rne(vk.x * sk + hk), f2bf_rne(vk.y * sk + hk),
                               f2bf_rne(vk.z * sk + hk), f2bf_rne(vk.w * sk + hk));
      *(short4*)(gsh + GQC + c * 528 + (ch + r * 4) * 2) = s4q;
      *(short4*)(gsh + GKC + c * 528 + (ch + r * 4) * 2) = s4k;
    }
  }
  __syncthreads();

  {
    int base = (wid >> 1) ? GKC : GQC;
    int gbase = (wid >> 1) ? GGK : GGQ;
    int rt = wid & 1;
    f32x4 acc0 = (f32x4){0.f, 0.f, 0.f, 0.f};
    f32x4 acc1 = (f32x4){0.f, 0.f, 0.f, 0.f};
#pragma unroll
    for (int ks = 0; ks < 8; ++ks) {
      bf16x8 af = *(const bf16x8*)(gsh + base + (rt * 16 + cg) * 528 + ks * 64 + hi * 16);
      bf16x8 b0 = *(const bf16x8*)(gsh + base + (cg) * 528 + ks * 64 + hi * 16);
      bf16x8 b1 = *(const bf16x8*)(gsh + base + (16 + cg) * 528 + ks * 64 + hi * 16);
      acc0 = __builtin_amdgcn_mfma_f32_16x16x32_bf16(af, b0, acc0, 0, 0, 0);
      acc1 = __builtin_amdgcn_mfma_f32_16x16x32_bf16(af, b1, acc1, 0, 0, 0);
    }
#pragma unroll
    for (int e = 0; e < 4; ++e) {
      int row = rt * 16 + hi * 4 + e;
      *(float*)(gsh + gbase + (row * 33 + cg) * 4) = acc0[e];
      *(float*)(gsh + gbase + (row * 33 + 16 + cg) * 4) = acc1[e];
    }
  }
  __syncthreads();

  float ssqk = 0.f;
#pragma unroll
  for (int pp = 0; pp < 4; ++pp) {
    int p = t * 4 + pp;
    int c = p >> 5, cp = p & 31;
    float gq = *(const float*)(gsh + GGQ + (c * 33 + cp) * 4);
    float gk = *(const float*)(gsh + GGK + (c * 33 + cp) * 4);
    ssqk += gq * gk;
  }
  float sq = 0.f, sk = 0.f;
  {
    int c = t >> 3, ch = (t & 7) * 32;
#pragma unroll 8
    for (int r = 0; r < 32; ++r) {
      sq += bf2f(*(const unsigned short*)(gsh + GQC + c * 528 + (ch + r) * 2));
      sk += bf2f(*(const unsigned short*)(gsh + GKC + c * 528 + (ch + r) * 2));
    }
  }
#pragma unroll
  for (int m = 1; m < 8; m <<= 1) { sq += __shfl_xor(sq, m); sk += __shfl_xor(sk, m); }
  float sprod = ((t & 7) == 0) ? sq * sk : 0.f;
#pragma unroll
  for (int m = 1; m < 64; m <<= 1) { ssqk += __shfl_xor(ssqk, m); sprod += __shfl_xor(sprod, m); }
  if (lane == 0) { r1[wid] = ssqk; r2[wid] = sprod; }
  __syncthreads();
  if (t == 0) {
    gpart[blockIdx.x * 2 + 0] = r1[0] + r1[1] + r1[2] + r1[3];
    gpart[blockIdx.x * 2 + 1] = r2[0] + r2[1] + r2[2] + r2[3];
  }
}

// ---------------- finalize: reduce partials + sim BN coefficients ----------------
__global__ void k_sim_finalize(const float* __restrict__ p1part,
                               const float* __restrict__ gpart,
                               const float* __restrict__ gs,
                               const float* __restrict__ bs,
                               float* __restrict__ simscale,
                               float* __restrict__ simshift) {
  __shared__ float sm[48];
  __shared__ float sh[24];
  const int t = threadIdx.x;
  if (t < 32) {
    int g = t & 7, stat = t >> 3;        // 0:s_qr 1:s_kr 2:ss_qr 3:ss_kr
    float s = 0.f;
    for (int i = 0; i < 256; ++i)        // 64 b x 4 it
      s += p1part[(((size_t)(i >> 2) * 8 + g) * 4 + (i & 3)) * 4 + stat];
    const float fs[4] = {F_QR, F_KR, F_QR * F_QR, F_KR * F_KR};
    const int dst[4] = {8, 16, 32, 40};
    sm[dst[stat] + g] = s * fs[stat];
  } else if (t < 48) {
    int g = t & 7, which = (t >> 3) & 1; // 0:ssqk 1:sprod(mean)
    float s = 0.f;
    for (int b = 0; b < 64; ++b) s += gpart[(b * 8 + g) * 2 + which];
    if (which) sm[g] = s; else sm[24 + g] = s;
  }
  __syncthreads();
  if (t < 24) {
    const float inv = 1.f / (64.f * 256.f * 256.f);
    float m = sm[t] * inv;
    float var = sm[24 + t] * inv - m * m;
    float a = gs[t] * rsqrtf(var + 1e-5f);
    simscale[t] = a;
    sh[t] = bs[t] - m * a;
  }
  __syncthreads();
  if (t < 8) simshift[t] = sh[t] + sh[8 + t] + sh[16 + t];
}

// ---------------- pass2: all-MFMA, 8 waves, pitched LDS (unchanged) -------
#define MG_OFF   0
#define SMX_OFF  0
#define SMS_OFF  512
#define KH_OFF   45056
#define KL_OFF   65536
#define RST_OFF  86016
#define QH_OFF   111616
#define QL_OFF   116736
#define VB_OFF   45056
#define PF_OFF   86016
#define RV_OFF   121856
#define P2_LDS   163840
#define MQP 656
#define GP  176
#define PFP 528
#define RVP 656

__global__ __launch_bounds__(512) void k_pass2(const float* __restrict__ qkv,
                                               const float* __restrict__ relp,
                                               const float* __restrict__ qs,
                                               const float* __restrict__ qh,
                                               const float* __restrict__ simscale,
                                               float* __restrict__ svbuf,
                                               float* __restrict__ svebuf) {
  extern __shared__ char lds[];
  const int it = blockIdx.x, bg = blockIdx.y;
  const int b = bg >> 3, g = bg & 7, i0 = it * 64;
  const int t = threadIdx.x, lane = t & 63, wid = t >> 6;
  const int cg = lane & 15, hi = lane >> 4;
  const int wi = wid & 3, wj = wid >> 2;
  const float aQK = simscale[g];
  const float aQR = F_QR * simscale[8 + g];
  const float aKR = F_KR * simscale[16 + g];

  {
    int c = t >> 4;
    int o = g * 128 + c;
    float sc = qs[o], hh = qh[o];
    int i4 = (t & 15) * 4;
    float4 v = *(const float4*)(qkv + ((size_t)b * OO + o) * NN + i0 + i4);
    float vv[4] = {v.x * sc + hh, v.y * sc + hh, v.z * sc + hh, v.w * sc + hh};
#pragma unroll
    for (int e = 0; e < 4; ++e) {
      int iL = i4 + e;
      unsigned short hb = (unsigned short)(__float_as_uint(vv[e]) >> 16);
      *(unsigned short*)(lds + QH_OFF + iL * QP + c * 2) = hb;
      *(unsigned short*)(lds + QL_OFF + iL * QP + c * 2) = f2bf_rne(vv[e] - bf2f(hb));
    }
  }
  {
    int c = t >> 4;
    int o = g * 128 + 32 + c;
    float sc = qs[o], hh = qh[o];
    const float* src = qkv + ((size_t)b * OO + o) * NN;
#pragma unroll
    for (int r = 0; r < 4; ++r) {
      int j4 = ((t & 15) + 16 * r) * 4;
      float4 v = *(const float4*)(src + j4);
      float vv[4] = {v.x * sc + hh, v.y * sc + hh, v.z * sc + hh, v.w * sc + hh};
#pragma unroll
      for (int e = 0; e < 4; ++e) {
        int j = j4 + e;
        unsigned short hb = (unsigned short)(__float_as_uint(vv[e]) >> 16);
        *(unsigned short*)(lds + KH_OFF + j * QP + c * 2) = hb;
        *(unsigned short*)(lds + KL_OFF + j * QP + c * 2) = f2bf_rne(vv[e] - bf2f(hb));
      }
    }
  }
  {
    int c = t >> 4;
    const float* src = relp + c * 512 + i0;
#pragma unroll
    for (int r = 0; r < 5; ++r) {
      int u4 = ((t & 15) + 16 * r) * 4;
      float4 v = *(const float4*)(src + u4);
      float vv[4] = {v.x, v.y, v.z, v.w};
#pragma unroll
      for (int e = 0; e < 4; ++e)
        *(unsigned short*)(lds + RST_OFF + (u4 + e) * QP + c * 2) = f2bf_rne(vv[e]);
    }
  }
  __syncthreads();

  f32x4 p[8];
#pragma unroll
  for (int n = 0; n < 8; ++n) p[n] = (f32x4){0.f, 0.f, 0.f, 0.f};

  int qrow = wi * 16 + cg;
  bf16x8 qhf = *(const bf16x8*)(lds + QH_OFF + qrow * QP + hi * 16);
  bf16x8 qlf = *(const bf16x8*)(lds + QL_OFF + qrow * QP + hi * 16);
#pragma unroll
  for (int n = 0; n < 8; ++n) {
    int krow = (wj * 8 + n) * 16 + cg;
    bf16x8 khf = *(const bf16x8*)(lds + KH_OFF + krow * QP + hi * 16);
    bf16x8 klf = *(const bf16x8*)(lds + KL_OFF + krow * QP + hi * 16);
    p[n] = __builtin_amdgcn_mfma_f32_16x16x32_bf16(qhf, khf, p[n], 0, 0, 0);
    p[n] = __builtin_amdgcn_mfma_f32_16x16x32_bf16(qhf, klf, p[n], 0, 0, 0);
    p[n] = __builtin_amdgcn_mfma_f32_16x16x32_bf16(qlf, khf, p[n], 0, 0, 0);
  }
#pragma unroll
  for (int n = 0; n < 8; ++n)
#pragma unroll
    for (int e = 0; e < 4; ++e) p[n][e] *= aQK;

#pragma unroll
  for (int m5 = 0; m5 < 10; ++m5) {
    int ntq = wj * 10 + m5;
    bf16x8 rf = *(const bf16x8*)(lds + RST_OFF + (ntq * 16 + cg) * QP + hi * 16);
    f32x4 m = (f32x4){0.f, 0.f, 0.f, 0.f};
    m = __builtin_amdgcn_mfma_f32_16x16x32_bf16(qhf, rf, m, 0, 0, 0);
#pragma unroll
    for (int e = 0; e < 4; ++e) {
      int iL = wi * 16 + hi * 4 + e;
      *(unsigned short*)(lds + MG_OFF + iL * MQP + (ntq * 16 + cg) * 2) = f2bf_rne(m[e]);
    }
  }
  __syncthreads();

#pragma unroll
  for (int n = 0; n < 8; ++n)
#pragma unroll
    for (int e = 0; e < 4; ++e) {
      int iL = wi * 16 + hi * 4 + e;
      int ul = iL - ((wj * 8 + n) * 16 + cg) + 255;
      p[n][e] += aQR * bf2f(*(const unsigned short*)(lds + MG_OFF + iL * MQP + ul * 2));
    }
  {
    int c = t >> 4;
    const float* src = relp + (32 + c) * 512 + (192 - i0);
#pragma unroll
    for (int r = 0; r < 5; ++r) {
      int u4 = ((t & 15) + 16 * r) * 4;
      float4 v = *(const float4*)(src + u4);
      float vv[4] = {v.x, v.y, v.z, v.w};
#pragma unroll
      for (int e = 0; e < 4; ++e)
        *(unsigned short*)(lds + RST_OFF + (u4 + e) * QP + c * 2) = f2bf_rne(vv[e]);
    }
  }
  __syncthreads();

#pragma unroll
  for (int jj = 0; jj < 2; ++jj) {
    int jt = wid * 2 + jj;
    bf16x8 kf = *(const bf16x8*)(lds + KH_OFF + (jt * 16 + cg) * QP + hi * 16);
#pragma unroll
    for (int n5 = 0; n5 < 5; ++n5) {
      bf16x8 rf = *(const bf16x8*)(lds + RST_OFF + ((jt + n5) * 16 + cg) * QP + hi * 16);
      f32x4 gacc = (f32x4){0.f, 0.f, 0.f, 0.f};
      gacc = __builtin_amdgcn_mfma_f32_16x16x32_bf16(kf, rf, gacc, 0, 0, 0);
#pragma unroll
      for (int e = 0; e < 4; ++e) {
        int j = jt * 16 + hi * 4 + e;
        *(unsigned short*)(lds + MG_OFF + j * GP + (n5 * 16 + cg) * 2) = f2bf_rne(gacc[e]);
      }
    }
  }
  __syncthreads();

#pragma unroll
  for (int n = 0; n < 8; ++n)
#pragma unroll
    for (int e = 0; e < 4; ++e) {
      int iL = wi * 16 + hi * 4 + e;
      int j = (wj * 8 + n) * 16 + cg;
      int sl = cg + 63 - iL;
      p[n][e] += aKR * bf2f(*(const unsigned short*)(lds + MG_OFF + j * GP + sl * 2));
    }
  __syncthreads();

  {
    float mloc[4];
#pragma unroll
    for (int e = 0; e < 4; ++e) {
      float m = p[0][e];
#pragma unroll
      for (int n = 1; n < 8; ++n) m = fmaxf(m, p[n][e]);
#pragma unroll
      for (int k = 1; k < 16; k <<= 1) m = fmaxf(m, __shfl_xor(m, k));
      mloc[e] = m;
    }
    if (cg == 0) {
#pragma unroll
      for (int e = 0; e < 4; ++e)
        *(float*)(lds + SMX_OFF + (wj * 64 + wi * 16 + hi * 4 + e) * 4) = mloc[e];
    }
    __syncthreads();
    float sloc[4];
#pragma unroll
    for (int e = 0; e < 4; ++e) {
      int iL = wi * 16 + hi * 4 + e;
      float m = fmaxf(*(const float*)(lds + SMX_OFF + iL * 4),
                      *(const float*)(lds + SMX_OFF + (64 + iL) * 4));
      float s = 0.f;
#pragma unroll
      for (int n = 0; n < 8; ++n) { float ev = __expf(p[n][e] - m); p[n][e] = ev; s += ev; }
#pragma unroll
      for (int k = 1; k < 16; k <<= 1) s += __shfl_xor(s, k);
      sloc[e] = s;
    }
    if (cg == 0) {
#pragma unroll
      for (int e = 0; e < 4; ++e)
        *(float*)(lds + SMS_OFF + (wj * 64 + wi * 16 + hi * 4 + e) * 4) = sloc[e];
    }
    __syncthreads();
#pragma unroll
    for (int e = 0; e < 4; ++e) {
      int iL = wi * 16 + hi * 4 + e;
      float s = *(const float*)(lds + SMS_OFF + iL * 4) +
                *(const float*)(lds + SMS_OFF + (64 + iL) * 4);
      float inv = 1.f / s;
#pragma unroll
      for (int n = 0; n < 8; ++n) p[n][e] *= inv;
    }
  }
  __syncthreads();

#pragma unroll
  for (int r = 0; r < 6; ++r) {
    int idx = r * 512 + t;
    if (idx < 2816) *(float4*)(lds + idx * 16) = make_float4(0.f, 0.f, 0.f, 0.f);
  }
  __syncthreads();

#pragma unroll
  for (int n = 0; n < 8; ++n)
#pragma unroll
    for (int e = 0; e < 4; ++e) {
      int iL = wi * 16 + hi * 4 + e;
      int j = (wj * 8 + n) * 16 + cg;
      unsigned short hv = f2bf_rne(p[n][e]);
      *(unsigned short*)(lds + PF_OFF + iL * PFP + j * 2) = hv;
      int us = iL + 255 - j;
      *(unsigned short*)(lds + MG_OFF + iL * MQP + us * 2) = hv;
    }
  {
    int cp = (t >> 2) & 63, half = t >> 8;
    int o = g * 128 + 64 + cp;
    float sc = qs[o], hh = qh[o];
    const float* src = qkv + ((size_t)b * OO + o) * NN;
#pragma unroll
    for (int r = 0; r < 8; ++r) {
      int ch = (t & 3) + half * 4 + 8 * r;
      float4 v = *(const float4*)(src + ch * 4);
      short4 s4 = make_short4(f2bf_rne(v.x * sc + hh), f2bf_rne(v.y * sc + hh),
                              f2bf_rne(v.z * sc + hh), f2bf_rne(v.w * sc + hh));
      *(short4*)(lds + VB_OFF + cp * PFP + ch * 8) = s4;
    }
    const float* srv = relp + (size_t)(64 + cp) * 512 + i0;
#pragma unroll
    for (int r = 0; r < 10; ++r) {
      int ch = (t & 3) + half * 4 + 8 * r;
      float4 v = *(const float4*)(srv + ch * 4);
      short4 s4 = make_short4(f2bf_rne(v.x), f2bf_rne(v.y), f2bf_rne(v.z), f2bf_rne(v.w));
      *(short4*)(lds + RV_OFF + cp * RVP + ch * 8) = s4;
    }
  }
  __syncthreads();

  {
    int prow = wi * 16 + cg;
    bf16x8 af[8];
#pragma unroll
    for (int ks = 0; ks < 8; ++ks)
      af[ks] = *(const bf16x8*)(lds + PF_OFF + prow * PFP + ks * 64 + hi * 16);
#pragma unroll
    for (int n = 0; n < 2; ++n) {
      int ntv = wj * 2 + n;
      f32x4 acc = (f32x4){0.f, 0.f, 0.f, 0.f};
#pragma unroll
      for (int ks = 0; ks < 8; ++ks) {
        bf16x8 bfv = *(const bf16x8*)(lds + VB_OFF + (ntv * 16 + cg) * PFP + ks * 64 + hi * 16);
        acc = __builtin_amdgcn_mfma_f32_16x16x32_bf16(af[ks], bfv, acc, 0, 0, 0);
      }
      float* dst = svbuf + ((size_t)(b * 512 + g * 64 + ntv * 16 + cg)) * NN + i0 + wi * 16 + hi * 4;
      *(float4*)dst = make_float4(acc[0], acc[1], acc[2], acc[3]);
    }
    bf16x8 ae[10];
#pragma unroll
    for (int ks = 0; ks < 10; ++ks)
      ae[ks] = *(const bf16x8*)(lds + MG_OFF + prow * MQP + ks * 64 + hi * 16);
#pragma unroll
    for (int n = 0; n < 2; ++n) {
      int ntv = wj * 2 + n;
      f32x4 acc = (f32x4){0.f, 0.f, 0.f, 0.f};
#pragma unroll
      for (int ks = 0; ks < 10; ++ks) {
        bf16x8 bfr = *(const bf16x8*)(lds + RV_OFF + (ntv * 16 + cg) * RVP + ks * 64 + hi * 16);
        acc = __builtin_amdgcn_mfma_f32_16x16x32_bf16(ae[ks], bfr, acc, 0, 0, 0);
      }
      float* dst = svebuf + ((size_t)(b * 512 + g * 64 + ntv * 16 + cg)) * NN + i0 + wi * 16 + hi * 4;
      *(float4*)dst = make_float4(acc[0] * F_SVE, acc[1] * F_SVE, acc[2] * F_SVE, acc[3] * F_SVE);
    }
  }
}

// ---------------- K6: final BN stats over sv / sve ----------------
__global__ __launch_bounds__(256) void k_out_stats(const float* __restrict__ svbuf,
                                                   const float* __restrict__ svebuf,
                                                   const float* __restrict__ go,
                                                   const float* __restrict__ bo,
                                                   float* __restrict__ osc,
                                                   float* __restrict__ osh) {
  const int bid = blockIdx.x;
  const int arr = bid >> 9, pch = bid & 511;
  const float* buf = arr ? svebuf : svbuf;
  const int t = threadIdx.x;
  float s = 0.f, ss = 0.f;
  for (int b = 0; b < BB; ++b) {
    float v = buf[((size_t)b * 512 + pch) * NN + t];
    s += v; ss += v * v;
  }
#pragma unroll
  for (int m = 1; m < 64; m <<= 1) { s += __shfl_xor(s, m); ss += __shfl_xor(ss, m); }
  __shared__ float rs[4], rss[4];
  int wv = t >> 6;
  if ((t & 63) == 0) { rs[wv] = s; rss[wv] = ss; }
  __syncthreads();
  if (t == 0) {
    s = rs[0] + rs[1] + rs[2] + rs[3];
    ss = rss[0] + rss[1] + rss[2] + rss[3];
    const float inv = 1.f / 16384.f;
    float m = s * inv;
    float var = ss * inv - m * m;
    float r = rsqrtf(var + 1e-5f);
    int o = pch * 2 + arr;
    float sc = go[o] * r;
    osc[bid] = sc;
    osh[bid] = bo[o] - m * sc;
  }
}

// ---------------- K7: combine ----------------
__global__ __launch_bounds__(256) void k_final(const float* __restrict__ svbuf,
                                               const float* __restrict__ svebuf,
                                               const float* __restrict__ osc,
                                               const float* __restrict__ osh,
                                               float* __restrict__ out) {
  const size_t f = (size_t)blockIdx.x * 256 + threadIdx.x;
  const int pch = (int)((f >> 6) & 511);
  float4 a = ((const float4*)svbuf)[f];
  float4 e = ((const float4*)svebuf)[f];
  float s1 = osc[pch], h1 = osh[pch];
  float s2 = osc[512 + pch], h2 = osh[512 + pch];
  float hh = h1 + h2;
  float4 o;
  o.x = a.x * s1 + e.x * s2 + hh;
  o.y = a.y * s1 + e.y * s2 + hh;
  o.z = a.z * s1 + e.z * s2 + hh;
  o.w = a.w * s1 + e.w * s2 + hh;
  ((float4*)out)[f] = o;
}

extern "C" void kernel_launch(void* const* d_in, const int* in_sizes, int n_in,
                              void* d_out, int out_size, void* d_ws, size_t ws_size,
                              hipStream_t stream) {
  const float* x     = (const float*)d_in[0];
  const float* w     = (const float*)d_in[1];
  const float* rel   = (const float*)d_in[2];
  const float* g_qkv = (const float*)d_in[3];
  const float* b_qkv = (const float*)d_in[4];
  const float* g_sim = (const float*)d_in[5];
  const float* b_sim = (const float*)d_in[6];
  const float* g_out = (const float*)d_in[7];
  const float* b_out = (const float*)d_in[8];

  float* ws = (float*)d_ws;
  float* qkv      = ws;
  float* sv       = qkv + 16777216;
  float* sve      = sv + 8388608;
  float* qs       = sve + 8388608;
  float* qh       = qs + 1024;
  float* simscale = qh + 1024;        // 24
  float* simshift = simscale + 24;    // 8
  float* osc      = simshift + 8;     // 1024
  float* osh      = osc + 1024;       // 1024
  float* p1part   = osh + 1024;       // 8192 (2048 blocks x 4 stats)
  float* gpart    = p1part + 8192;    // 1024 (512 blocks x 2)

  float* relp = (float*)d_out;

  // split-bf16 copies of x and w alias sv/sve (dead until k_pass2, which runs
  // after k_qkv_gemm has fully consumed them).
  unsigned short* xh = (unsigned short*)sv;      // 8,388,608 shorts
  unsigned short* xl = xh + 8388608;             // 8,388,608 shorts (= sv fully)
  unsigned short* wh = (unsigned short*)sve;     // 524,288 shorts
  unsigned short* wl = wh + 524288;              // 524,288 shorts

  hipFuncSetAttribute((const void*)k_pass2, hipFuncAttributeMaxDynamicSharedMemorySize, P2_LDS);
  hipFuncSetAttribute((const void*)k_p1lite, hipFuncAttributeMaxDynamicSharedMemorySize, P1_LDS);

  k_relpad<<<128, 256, 0, stream>>>(rel, relp);
  k_split<<<2048, 256, 0, stream>>>(x, xh, xl, 2097152);
  k_split<<<512, 256, 0, stream>>>(w, wh, wl, 131072);
  k_qkv_gemm<<<dim3(2, 8, 64), 256, 0, stream>>>(xh, xl, wh, wl, qkv);
  k_qkv_stats<<<1024, 256, 0, stream>>>(qkv, g_qkv, b_qkv, qs, qh);
  k_p1lite<<<dim3(4, 512), 512, P1_LDS, stream>>>(qkv, relp, qs, qh, p1part);
  k_gram<<<512, 256, 0, stream>>>(qkv, qs, qh, gpart);
  k_sim_finalize<<<1, 64, 0, stream>>>(p1part, gpart, g_sim, b_sim, simscale, simshift);
  k_pass2<<<dim3(4, 512), 512, P2_LDS, stream>>>(qkv, relp, qs, qh, simscale, sv, sve);
  k_out_stats<<<1024, 256, 0, stream>>>(sv, sve, g_out, b_out, osc, osh);
  k_final<<<8192, 256, 0, stream>>>(sv, sve, osc, osh, (float*)d_out);
}